// Round 4
// baseline (788.629 us; speedup 1.0000x reference)
//
#include <hip/hip_runtime.h>
#include <stdint.h>

#define B_ 4
#define C_ 256
#define H_ 64
#define W_ 64
#define O_ 256
#define K_ 2304    // C_*9, tap-major: kk = k*256 + c
#define HW 4096
#define NPIX 16384

typedef unsigned short u16;
typedef __attribute__((ext_vector_type(8))) short bf16x8;
typedef __attribute__((ext_vector_type(4))) float f32x4;

__device__ __forceinline__ u16 f2bf(float f) {
    union { float f; uint32_t u; } v; v.f = f;
    uint32_t u = v.u;
    return (u16)((u + 0x7FFFu + ((u >> 16) & 1u)) >> 16);
}

// ---------------- Kernel 1: scale + mask conv3x3 (partial over 64-ch group) ----
// grid (B*H, 4): bh, channel-group. 512 threads: lane = w pixel, wave = 8-ch slice.
// part[cg][bh][10][64] fp32 partial sums.
__global__ __launch_bounds__(512) void k_scale_mask(
    const float* __restrict__ x, const float* __restrict__ w_scale,
    const float* __restrict__ w_mask, float* __restrict__ part)
{
    int bh = blockIdx.x;           // 0..255
    int cg = blockIdx.y;           // 0..3
    int b = bh >> 6, h = bh & 63;
    int tid = threadIdx.x;
    int w = tid & 63;
    int wv = tid >> 6;             // 0..7

    float acc[10];
#pragma unroll
    for (int o = 0; o < 10; ++o) acc[o] = 0.f;

    const float* xb = x + (size_t)b * (C_ * HW);
#pragma unroll
    for (int cc = 0; cc < 8; ++cc) {
        int c = cg * 64 + wv * 8 + cc;
        const float* xp = xb + c * HW;
        float xv[9];
#pragma unroll
        for (int dy = -1; dy <= 1; ++dy) {
            int hh = h + dy;
            bool hv = (hh >= 0) && (hh < 64);
#pragma unroll
            for (int dx = -1; dx <= 1; ++dx) {
                int ww = w + dx;
                bool vld = hv && (ww >= 0) && (ww < 64);
                xv[(dy + 1) * 3 + (dx + 1)] = vld ? xp[hh * 64 + ww] : 0.f;
            }
        }
        const float* wsc = w_scale + c * 9;
#pragma unroll
        for (int k = 0; k < 9; ++k) acc[0] = fmaf(xv[k], wsc[k], acc[0]);
#pragma unroll
        for (int j = 0; j < 9; ++j) {
            const float* wm = w_mask + ((size_t)(j * C_ + c)) * 9;
#pragma unroll
            for (int k = 0; k < 9; ++k) acc[1 + j] = fmaf(xv[k], wm[k], acc[1 + j]);
        }
    }

    __shared__ float red[10 * 8 * 64];
#pragma unroll
    for (int o = 0; o < 10; ++o) red[(o * 8 + wv) * 64 + w] = acc[o];
    __syncthreads();
    if (tid < 64) {
        float* pout = part + ((size_t)(cg * 256 + bh) * 10) * 64 + tid;
#pragma unroll
        for (int o = 0; o < 10; ++o) {
            float t = 0.f;
#pragma unroll
            for (int g = 0; g < 8; ++g) t += red[(o * 8 + g) * 64 + tid];
            pout[o * 64] = t;
        }
    }
}

// ---------------- Kernel 1b: finalize scale/mask ----------------
// grid 64 blocks x 256 threads; thread = (bh, w).
__global__ __launch_bounds__(256) void k_finalize(
    const float* __restrict__ part, const float* __restrict__ b_scale,
    const float* __restrict__ b_mask, float* __restrict__ scale_o,
    float* __restrict__ mask_o)
{
    int tid = threadIdx.x;
    int bh = blockIdx.x * 4 + (tid >> 6);
    int w = tid & 63;
    int b = bh >> 6, h = bh & 63;
#pragma unroll
    for (int o = 0; o < 10; ++o) {
        float t = 0.f;
#pragma unroll
        for (int cg = 0; cg < 4; ++cg)
            t += part[((size_t)(cg * 256 + bh) * 10 + o) * 64 + w];
        if (o == 0) {
            float s = t + b_scale[0];
            scale_o[bh * 64 + w] = s > 0.f ? s : 0.f;
        } else {
            float m = t + b_mask[o - 1];
            mask_o[(b * 9 + (o - 1)) * HW + h * 64 + w] = 1.f / (1.f + expf(-m));
        }
    }
}

// ---------------- Kernel 2: pack weight fp32 -> bf16, tap-major K ----------------
__global__ __launch_bounds__(256) void k_pack_w(const float* __restrict__ wgt,
                                                u16* __restrict__ wbf)
{
    int k = blockIdx.x, o = blockIdx.y, c = threadIdx.x;
    wbf[(size_t)o * K_ + k * 256 + c] = f2bf(wgt[(size_t)o * K_ + c * 9 + k]);
}

// ---------------- Kernel 2b: transpose x NCHW -> NHWC (xT[b][hw][c]) ----------------
__global__ __launch_bounds__(256) void k_transpose(const float* __restrict__ x,
                                                   float* __restrict__ xT)
{
    __shared__ float t[64][65];
    int tid = threadIdx.x;
    int hw0 = blockIdx.x * 64, c0 = blockIdx.y * 64, b = blockIdx.z;

    {
        int hw4 = (tid & 15) * 4;
        int cr = tid >> 4;                 // 0..15
        const float* xb = x + ((size_t)(b * 256 + c0)) * HW + hw0;
#pragma unroll
        for (int i = 0; i < 4; ++i) {
            int c = cr + i * 16;
            float4 v = *(const float4*)(xb + (size_t)c * HW + hw4);
            *(float4*)(&t[c][hw4]) = v;
        }
    }
    __syncthreads();
    {
        int c4 = (tid & 15) * 4;
        int hwr = tid >> 4;                // 0..15
        float* xo = xT + ((size_t)(b * HW + hw0)) * 256 + c0;
#pragma unroll
        for (int i = 0; i < 4; ++i) {
            int hwl = hwr + i * 16;
            float4 o;
            o.x = t[c4 + 0][hwl];
            o.y = t[c4 + 1][hwl];
            o.z = t[c4 + 2][hwl];
            o.w = t[c4 + 3][hwl];
            *(float4*)(xo + (size_t)hwl * 256 + c4) = o;
        }
    }
}

// ---------------- Kernel 3: build val[N][K] bf16 from NHWC x ----------------
__global__ __launch_bounds__(256) void k_val2(
    const float* __restrict__ xT, const float* __restrict__ scale_i,
    const float* __restrict__ mask_i, u16* __restrict__ val)
{
    int wv = threadIdx.x >> 6, lane = threadIdx.x & 63;
    int p = blockIdx.x * 4 + wv;
    int b = p >> 12, hw = p & 4095;
    int h = hw >> 6, w = hw & 63;
    float d = 1.f + scale_i[p];
    const float* xb = xT + ((size_t)(b << 12)) * 256;
    u16* vout = val + (size_t)p * K_;
    int c0 = lane * 4;

#pragma unroll 3
    for (int k = 0; k < 9; ++k) {
        int dy = k / 3 - 1, dx = k % 3 - 1;
        float ysf = (float)(h - 1) + (float)dy * d;
        float xsf = (float)(w - 1) + (float)dx * d;
        float y0f = floorf(ysf), x0f = floorf(xsf);
        float wy = ysf - y0f, wx = xsf - x0f;
        int y0 = (int)y0f, x0 = (int)x0f;
        int y1 = y0 + 1, x1 = x0 + 1;
        float vy0 = (y0 >= 0 && y0 < 64) ? 1.f : 0.f;
        float vy1 = (y1 >= 0 && y1 < 64) ? 1.f : 0.f;
        float vx0 = (x0 >= 0 && x0 < 64) ? 1.f : 0.f;
        float vx1 = (x1 >= 0 && x1 < 64) ? 1.f : 0.f;

        float m = mask_i[(b * 9 + k) * HW + hw];
        float w00 = (1.f - wy) * (1.f - wx) * m * vy0 * vx0;
        float w01 = (1.f - wy) * wx * m * vy0 * vx1;
        float w10 = wy * (1.f - wx) * m * vy1 * vx0;
        float w11 = wy * wx * m * vy1 * vx1;

        int cy0 = min(max(y0, 0), 63), cy1 = min(max(y1, 0), 63);
        int cx0 = min(max(x0, 0), 63), cx1 = min(max(x1, 0), 63);

        const float* p00 = xb + (size_t)(cy0 * 64 + cx0) * 256 + c0;
        const float* p01 = xb + (size_t)(cy0 * 64 + cx1) * 256 + c0;
        const float* p10 = xb + (size_t)(cy1 * 64 + cx0) * 256 + c0;
        const float* p11 = xb + (size_t)(cy1 * 64 + cx1) * 256 + c0;
        float4 v00 = *(const float4*)p00;
        float4 v01 = *(const float4*)p01;
        float4 v10 = *(const float4*)p10;
        float4 v11 = *(const float4*)p11;

        float rx = fmaf(w00, v00.x, fmaf(w01, v01.x, fmaf(w10, v10.x, w11 * v11.x)));
        float ry = fmaf(w00, v00.y, fmaf(w01, v01.y, fmaf(w10, v10.y, w11 * v11.y)));
        float rz = fmaf(w00, v00.z, fmaf(w01, v01.z, fmaf(w10, v10.z, w11 * v11.z)));
        float rw = fmaf(w00, v00.w, fmaf(w01, v01.w, fmaf(w10, v10.w, w11 * v11.w)));

        ushort4 pk;
        pk.x = f2bf(rx); pk.y = f2bf(ry); pk.z = f2bf(rz); pk.w = f2bf(rw);
        *(ushort4*)(vout + k * 256 + c0) = pk;
    }
}

// ---------------- Kernel 4: bf16 MFMA GEMM ----------------
__global__ __launch_bounds__(256) void k_gemm(
    const u16* __restrict__ wbf, const u16* __restrict__ val,
    const float* __restrict__ bias, float* __restrict__ out)
{
    __shared__ u16 As[128 * 40];
    __shared__ u16 Bs[128 * 40];
    int tid = threadIdx.x;
    int lane = tid & 63;
    int wv = tid >> 6;
    int wm = wv >> 1, wn = wv & 1;
    int n0 = blockIdx.x * 128;
    int m0 = blockIdx.y * 128;
    int l15 = lane & 15, l4 = lane >> 4;

    f32x4 acc[4][4];
#pragma unroll
    for (int i = 0; i < 4; ++i)
#pragma unroll
        for (int j = 0; j < 4; ++j) acc[i][j] = (f32x4){0.f, 0.f, 0.f, 0.f};

    int r0 = tid >> 2, q0 = tid & 3;
    int r1 = (tid + 256) >> 2;

    for (int k0 = 0; k0 < K_; k0 += 32) {
        uint4 a0 = *(const uint4*)(wbf + (size_t)(m0 + r0) * K_ + k0 + q0 * 8);
        uint4 a1 = *(const uint4*)(wbf + (size_t)(m0 + r1) * K_ + k0 + q0 * 8);
        uint4 b0 = *(const uint4*)(val + (size_t)(n0 + r0) * K_ + k0 + q0 * 8);
        uint4 b1 = *(const uint4*)(val + (size_t)(n0 + r1) * K_ + k0 + q0 * 8);
        __syncthreads();
        *(uint4*)(As + r0 * 40 + q0 * 8) = a0;
        *(uint4*)(As + r1 * 40 + q0 * 8) = a1;
        *(uint4*)(Bs + r0 * 40 + q0 * 8) = b0;
        *(uint4*)(Bs + r1 * 40 + q0 * 8) = b1;
        __syncthreads();

        bf16x8 af[4], bg[4];
#pragma unroll
        for (int i = 0; i < 4; ++i)
            af[i] = *(const bf16x8*)(As + (wm * 64 + i * 16 + l15) * 40 + l4 * 8);
#pragma unroll
        for (int j = 0; j < 4; ++j)
            bg[j] = *(const bf16x8*)(Bs + (wn * 64 + j * 16 + l15) * 40 + l4 * 8);
#pragma unroll
        for (int i = 0; i < 4; ++i)
#pragma unroll
            for (int j = 0; j < 4; ++j)
                acc[i][j] = __builtin_amdgcn_mfma_f32_16x16x32_bf16(af[i], bg[j], acc[i][j], 0, 0, 0);
    }

    int bidx = n0 >> 12;
    int hwbase = n0 & 4095;
#pragma unroll
    for (int i = 0; i < 4; ++i)
#pragma unroll
        for (int j = 0; j < 4; ++j)
#pragma unroll
            for (int t = 0; t < 4; ++t) {
                int row = wm * 64 + i * 16 + l4 * 4 + t;
                int col = wn * 64 + j * 16 + l15;
                int o = m0 + row;
                out[((size_t)(bidx * O_ + o)) * HW + hwbase + col] = acc[i][j][t] + bias[o];
            }
}

extern "C" void kernel_launch(void* const* d_in, const int* in_sizes, int n_in,
                              void* d_out, int out_size, void* d_ws, size_t ws_size,
                              hipStream_t stream) {
    const float* x       = (const float*)d_in[0];
    const float* weight  = (const float*)d_in[1];
    const float* bias    = (const float*)d_in[2];
    const float* w_scale = (const float*)d_in[3];
    const float* b_scale = (const float*)d_in[4];
    const float* w_mask  = (const float*)d_in[5];
    const float* b_mask  = (const float*)d_in[6];
    float* out = (float*)d_out;

    char* ws = (char*)d_ws;
    float* scale_ws = (float*)ws;                                  // 64 KB
    float* mask_ws  = (float*)(ws + 65536);                        // 576 KB
    u16*   wbf      = (u16*)(ws + 65536 + 589824);                 // 1.125 MB
    u16*   val      = (u16*)(ws + 65536 + 589824 + 1179648);       // 75.5 MB
    float* xT       = (float*)(ws + 65536 + 589824 + 1179648 + 75497472); // 64 MB
    // partials alias the val region: fully consumed by k_finalize before k_val2 writes val
    float* part_ws  = (float*)val;                                 // 2.62 MB

    k_scale_mask<<<dim3(B_ * H_, 4), 512, 0, stream>>>(x, w_scale, w_mask, part_ws);
    k_finalize<<<dim3(64), 256, 0, stream>>>(part_ws, b_scale, b_mask, scale_ws, mask_ws);
    k_pack_w<<<dim3(9, O_), 256, 0, stream>>>(weight, wbf);
    k_transpose<<<dim3(HW / 64, C_ / 64, B_), 256, 0, stream>>>(x, xT);
    k_val2<<<dim3(NPIX / 4), 256, 0, stream>>>(xT, scale_ws, mask_ws, val);
    k_gemm<<<dim3(NPIX / 128, O_ / 128), 256, 0, stream>>>(wbf, val, bias, out);
}

// Round 5
// 221.548 us; speedup vs baseline: 3.5596x; 3.5596x over previous
//
#include <hip/hip_runtime.h>
#include <stdint.h>

#define B_ 4
#define C_ 256
#define H_ 64
#define W_ 64
#define O_ 256
#define K_ 2304    // C_*9, tap-major: kk = k*256 + c
#define HW 4096
#define NPIX 16384

typedef unsigned short u16;
typedef __attribute__((ext_vector_type(8))) short bf16x8;
typedef __attribute__((ext_vector_type(4))) float f32x4;

__device__ __forceinline__ u16 f2bf(float f) {
    union { float f; uint32_t u; } v; v.f = f;
    uint32_t u = v.u;
    return (u16)((u + 0x7FFFu + ((u >> 16) & 1u)) >> 16);
}

// ---------------- Kernel 1: scale + mask conv3x3 (partial over 64-ch group) ----
// grid (B*H, 4): bh, channel-group. 512 threads: lane = w pixel, wave = 8-ch slice.
// part[cg][bh][10][64] fp32 partial sums.
// NOTE: channel loop MUST stay rolled (#pragma unroll 1): full unroll spills
// ~1.8KB/thread to scratch (R4: VGPR 128, 942MB scratch writes, 615us).
__global__ __launch_bounds__(512) void k_scale_mask(
    const float* __restrict__ x, const float* __restrict__ w_scale,
    const float* __restrict__ w_mask, float* __restrict__ part)
{
    int bh = blockIdx.x;           // 0..255
    int cg = blockIdx.y;           // 0..3
    int b = bh >> 6, h = bh & 63;
    int tid = threadIdx.x;
    int w = tid & 63;
    int wv = tid >> 6;             // 0..7

    float acc[10];
#pragma unroll
    for (int o = 0; o < 10; ++o) acc[o] = 0.f;

    const float* xb = x + (size_t)b * (C_ * HW);
#pragma unroll 1
    for (int cc = 0; cc < 8; ++cc) {
        int c = cg * 64 + wv * 8 + cc;
        const float* xp = xb + c * HW;
        float xv[9];
#pragma unroll
        for (int dy = -1; dy <= 1; ++dy) {
            int hh = h + dy;
            bool hv = (hh >= 0) && (hh < 64);
#pragma unroll
            for (int dx = -1; dx <= 1; ++dx) {
                int ww = w + dx;
                bool vld = hv && (ww >= 0) && (ww < 64);
                xv[(dy + 1) * 3 + (dx + 1)] = vld ? xp[hh * 64 + ww] : 0.f;
            }
        }
        const float* wsc = w_scale + c * 9;
#pragma unroll
        for (int k = 0; k < 9; ++k) acc[0] = fmaf(xv[k], wsc[k], acc[0]);
#pragma unroll
        for (int j = 0; j < 9; ++j) {
            const float* wm = w_mask + ((size_t)(j * C_ + c)) * 9;
#pragma unroll
            for (int k = 0; k < 9; ++k) acc[1 + j] = fmaf(xv[k], wm[k], acc[1 + j]);
        }
    }

    __shared__ float red[10 * 8 * 64];
#pragma unroll
    for (int o = 0; o < 10; ++o) red[(o * 8 + wv) * 64 + w] = acc[o];
    __syncthreads();
    if (tid < 64) {
        float* pout = part + ((size_t)(cg * 256 + bh) * 10) * 64 + tid;
#pragma unroll
        for (int o = 0; o < 10; ++o) {
            float t = 0.f;
#pragma unroll
            for (int g = 0; g < 8; ++g) t += red[(o * 8 + g) * 64 + tid];
            pout[o * 64] = t;
        }
    }
}

// ---------------- Kernel 1b: finalize scale/mask ----------------
__global__ __launch_bounds__(256) void k_finalize(
    const float* __restrict__ part, const float* __restrict__ b_scale,
    const float* __restrict__ b_mask, float* __restrict__ scale_o,
    float* __restrict__ mask_o)
{
    int tid = threadIdx.x;
    int bh = blockIdx.x * 4 + (tid >> 6);
    int w = tid & 63;
    int b = bh >> 6, h = bh & 63;
#pragma unroll
    for (int o = 0; o < 10; ++o) {
        float t = 0.f;
#pragma unroll
        for (int cg = 0; cg < 4; ++cg)
            t += part[((size_t)(cg * 256 + bh) * 10 + o) * 64 + w];
        if (o == 0) {
            float s = t + b_scale[0];
            scale_o[bh * 64 + w] = s > 0.f ? s : 0.f;
        } else {
            float m = t + b_mask[o - 1];
            mask_o[(b * 9 + (o - 1)) * HW + h * 64 + w] = 1.f / (1.f + expf(-m));
        }
    }
}

// ---------------- Kernel 2: pack weight fp32 -> bf16, tap-major K ----------------
__global__ __launch_bounds__(256) void k_pack_w(const float* __restrict__ wgt,
                                                u16* __restrict__ wbf)
{
    int k = blockIdx.x, o = blockIdx.y, c = threadIdx.x;
    wbf[(size_t)o * K_ + k * 256 + c] = f2bf(wgt[(size_t)o * K_ + c * 9 + k]);
}

// ---------------- Kernel 2b: transpose x NCHW -> NHWC (xT[b][hw][c]) ----------------
__global__ __launch_bounds__(256) void k_transpose(const float* __restrict__ x,
                                                   float* __restrict__ xT)
{
    __shared__ float t[64][65];
    int tid = threadIdx.x;
    int hw0 = blockIdx.x * 64, c0 = blockIdx.y * 64, b = blockIdx.z;

    {
        int hw4 = (tid & 15) * 4;
        int cr = tid >> 4;                 // 0..15
        const float* xb = x + ((size_t)(b * 256 + c0)) * HW + hw0;
#pragma unroll
        for (int i = 0; i < 4; ++i) {
            int c = cr + i * 16;
            float4 v = *(const float4*)(xb + (size_t)c * HW + hw4);
            *(float4*)(&t[c][hw4]) = v;
        }
    }
    __syncthreads();
    {
        int c4 = (tid & 15) * 4;
        int hwr = tid >> 4;                // 0..15
        float* xo = xT + ((size_t)(b * HW + hw0)) * 256 + c0;
#pragma unroll
        for (int i = 0; i < 4; ++i) {
            int hwl = hwr + i * 16;
            float4 o;
            o.x = t[c4 + 0][hwl];
            o.y = t[c4 + 1][hwl];
            o.z = t[c4 + 2][hwl];
            o.w = t[c4 + 3][hwl];
            *(float4*)(xo + (size_t)hwl * 256 + c4) = o;
        }
    }
}

// ---------------- Kernel 3: build val[N][K] bf16 from NHWC x ----------------
__global__ __launch_bounds__(256) void k_val2(
    const float* __restrict__ xT, const float* __restrict__ scale_i,
    const float* __restrict__ mask_i, u16* __restrict__ val)
{
    int wv = threadIdx.x >> 6, lane = threadIdx.x & 63;
    int p = blockIdx.x * 4 + wv;
    int b = p >> 12, hw = p & 4095;
    int h = hw >> 6, w = hw & 63;
    float d = 1.f + scale_i[p];
    const float* xb = xT + ((size_t)(b << 12)) * 256;
    u16* vout = val + (size_t)p * K_;
    int c0 = lane * 4;

#pragma unroll 3
    for (int k = 0; k < 9; ++k) {
        int dy = k / 3 - 1, dx = k % 3 - 1;
        float ysf = (float)(h - 1) + (float)dy * d;
        float xsf = (float)(w - 1) + (float)dx * d;
        float y0f = floorf(ysf), x0f = floorf(xsf);
        float wy = ysf - y0f, wx = xsf - x0f;
        int y0 = (int)y0f, x0 = (int)x0f;
        int y1 = y0 + 1, x1 = x0 + 1;
        float vy0 = (y0 >= 0 && y0 < 64) ? 1.f : 0.f;
        float vy1 = (y1 >= 0 && y1 < 64) ? 1.f : 0.f;
        float vx0 = (x0 >= 0 && x0 < 64) ? 1.f : 0.f;
        float vx1 = (x1 >= 0 && x1 < 64) ? 1.f : 0.f;

        float m = mask_i[(b * 9 + k) * HW + hw];
        float w00 = (1.f - wy) * (1.f - wx) * m * vy0 * vx0;
        float w01 = (1.f - wy) * wx * m * vy0 * vx1;
        float w10 = wy * (1.f - wx) * m * vy1 * vx0;
        float w11 = wy * wx * m * vy1 * vx1;

        int cy0 = min(max(y0, 0), 63), cy1 = min(max(y1, 0), 63);
        int cx0 = min(max(x0, 0), 63), cx1 = min(max(x1, 0), 63);

        const float* p00 = xb + (size_t)(cy0 * 64 + cx0) * 256 + c0;
        const float* p01 = xb + (size_t)(cy0 * 64 + cx1) * 256 + c0;
        const float* p10 = xb + (size_t)(cy1 * 64 + cx0) * 256 + c0;
        const float* p11 = xb + (size_t)(cy1 * 64 + cx1) * 256 + c0;
        float4 v00 = *(const float4*)p00;
        float4 v01 = *(const float4*)p01;
        float4 v10 = *(const float4*)p10;
        float4 v11 = *(const float4*)p11;

        float rx = fmaf(w00, v00.x, fmaf(w01, v01.x, fmaf(w10, v10.x, w11 * v11.x)));
        float ry = fmaf(w00, v00.y, fmaf(w01, v01.y, fmaf(w10, v10.y, w11 * v11.y)));
        float rz = fmaf(w00, v00.z, fmaf(w01, v01.z, fmaf(w10, v10.z, w11 * v11.z)));
        float rw = fmaf(w00, v00.w, fmaf(w01, v01.w, fmaf(w10, v10.w, w11 * v11.w)));

        ushort4 pk;
        pk.x = f2bf(rx); pk.y = f2bf(ry); pk.z = f2bf(rz); pk.w = f2bf(rw);
        *(ushort4*)(vout + k * 256 + c0) = pk;
    }
}

// ---------------- Kernel 4: bf16 MFMA GEMM ----------------
__global__ __launch_bounds__(256) void k_gemm(
    const u16* __restrict__ wbf, const u16* __restrict__ val,
    const float* __restrict__ bias, float* __restrict__ out)
{
    __shared__ u16 As[128 * 40];
    __shared__ u16 Bs[128 * 40];
    int tid = threadIdx.x;
    int lane = tid & 63;
    int wv = tid >> 6;
    int wm = wv >> 1, wn = wv & 1;
    int n0 = blockIdx.x * 128;
    int m0 = blockIdx.y * 128;
    int l15 = lane & 15, l4 = lane >> 4;

    f32x4 acc[4][4];
#pragma unroll
    for (int i = 0; i < 4; ++i)
#pragma unroll
        for (int j = 0; j < 4; ++j) acc[i][j] = (f32x4){0.f, 0.f, 0.f, 0.f};

    int r0 = tid >> 2, q0 = tid & 3;
    int r1 = (tid + 256) >> 2;

    for (int k0 = 0; k0 < K_; k0 += 32) {
        uint4 a0 = *(const uint4*)(wbf + (size_t)(m0 + r0) * K_ + k0 + q0 * 8);
        uint4 a1 = *(const uint4*)(wbf + (size_t)(m0 + r1) * K_ + k0 + q0 * 8);
        uint4 b0 = *(const uint4*)(val + (size_t)(n0 + r0) * K_ + k0 + q0 * 8);
        uint4 b1 = *(const uint4*)(val + (size_t)(n0 + r1) * K_ + k0 + q0 * 8);
        __syncthreads();
        *(uint4*)(As + r0 * 40 + q0 * 8) = a0;
        *(uint4*)(As + r1 * 40 + q0 * 8) = a1;
        *(uint4*)(Bs + r0 * 40 + q0 * 8) = b0;
        *(uint4*)(Bs + r1 * 40 + q0 * 8) = b1;
        __syncthreads();

        bf16x8 af[4], bg[4];
#pragma unroll
        for (int i = 0; i < 4; ++i)
            af[i] = *(const bf16x8*)(As + (wm * 64 + i * 16 + l15) * 40 + l4 * 8);
#pragma unroll
        for (int j = 0; j < 4; ++j)
            bg[j] = *(const bf16x8*)(Bs + (wn * 64 + j * 16 + l15) * 40 + l4 * 8);
#pragma unroll
        for (int i = 0; i < 4; ++i)
#pragma unroll
            for (int j = 0; j < 4; ++j)
                acc[i][j] = __builtin_amdgcn_mfma_f32_16x16x32_bf16(af[i], bg[j], acc[i][j], 0, 0, 0);
    }

    int bidx = n0 >> 12;
    int hwbase = n0 & 4095;
#pragma unroll
    for (int i = 0; i < 4; ++i)
#pragma unroll
        for (int j = 0; j < 4; ++j)
#pragma unroll
            for (int t = 0; t < 4; ++t) {
                int row = wm * 64 + i * 16 + l4 * 4 + t;
                int col = wn * 64 + j * 16 + l15;
                int o = m0 + row;
                out[((size_t)(bidx * O_ + o)) * HW + hwbase + col] = acc[i][j][t] + bias[o];
            }
}

extern "C" void kernel_launch(void* const* d_in, const int* in_sizes, int n_in,
                              void* d_out, int out_size, void* d_ws, size_t ws_size,
                              hipStream_t stream) {
    const float* x       = (const float*)d_in[0];
    const float* weight  = (const float*)d_in[1];
    const float* bias    = (const float*)d_in[2];
    const float* w_scale = (const float*)d_in[3];
    const float* b_scale = (const float*)d_in[4];
    const float* w_mask  = (const float*)d_in[5];
    const float* b_mask  = (const float*)d_in[6];
    float* out = (float*)d_out;

    char* ws = (char*)d_ws;
    float* scale_ws = (float*)ws;                                  // 64 KB
    float* mask_ws  = (float*)(ws + 65536);                        // 576 KB
    u16*   wbf      = (u16*)(ws + 65536 + 589824);                 // 1.125 MB
    u16*   val      = (u16*)(ws + 65536 + 589824 + 1179648);       // 75.5 MB
    float* xT       = (float*)(ws + 65536 + 589824 + 1179648 + 75497472); // 64 MB
    // partials alias the val region: fully consumed by k_finalize before k_val2 writes val
    float* part_ws  = (float*)val;                                 // 2.62 MB

    k_scale_mask<<<dim3(B_ * H_, 4), 512, 0, stream>>>(x, w_scale, w_mask, part_ws);
    k_finalize<<<dim3(64), 256, 0, stream>>>(part_ws, b_scale, b_mask, scale_ws, mask_ws);
    k_pack_w<<<dim3(9, O_), 256, 0, stream>>>(weight, wbf);
    k_transpose<<<dim3(HW / 64, C_ / 64, B_), 256, 0, stream>>>(x, xT);
    k_val2<<<dim3(NPIX / 4), 256, 0, stream>>>(xT, scale_ws, mask_ws, val);
    k_gemm<<<dim3(NPIX / 128, O_ / 128), 256, 0, stream>>>(wbf, val, bias, out);
}

// Round 6
// 200.826 us; speedup vs baseline: 3.9269x; 1.1032x over previous
//
#include <hip/hip_runtime.h>
#include <stdint.h>

#define B_ 4
#define C_ 256
#define H_ 64
#define W_ 64
#define O_ 256
#define K_ 2304    // C_*9, tap-major: kk = k*256 + c
#define HW 4096
#define NPIX 16384

typedef unsigned short u16;
typedef __attribute__((ext_vector_type(8))) short bf16x8;
typedef __attribute__((ext_vector_type(4))) float f32x4;

__device__ __forceinline__ u16 f2bf(float f) {
    union { float f; uint32_t u; } v; v.f = f;
    uint32_t u = v.u;
    return (u16)((u + 0x7FFFu + ((u >> 16) & 1u)) >> 16);
}

// ---------------- Kernel 1: scale + mask conv3x3 (partial over 64-ch group) ----
// grid (B*H, 4): bh, channel-group. 512 threads: lane = w pixel, wave = 8-ch slice.
// part[cg][bh][10][64] fp32 partial sums.
// R5 lesson: kernel was VMEM-instruction-bound (6.5M loads, 90/99 per iter are
// broadcast weight loads). Stage weights in LDS; inner loop reads LDS broadcast.
// Channel loop stays rolled (R4: full unroll -> 1.8KB/thread scratch spill).
__global__ __launch_bounds__(512) void k_scale_mask(
    const float* __restrict__ x, const float* __restrict__ w_scale,
    const float* __restrict__ w_mask, float* __restrict__ part)
{
    __shared__ float wsm[64 * 90];   // [c_local][90]: 0..8 w_scale, 9+j*9+k w_mask
    __shared__ float red[10 * 8 * 64];

    int bh = blockIdx.x;           // 0..255
    int cg = blockIdx.y;           // 0..3
    int b = bh >> 6, h = bh & 63;
    int tid = threadIdx.x;
    int w = tid & 63;
    int wv = tid >> 6;             // 0..7

    // stage weight slice for this channel group: 5760 floats, coalesced-ish
    for (int i = tid; i < 64 * 90; i += 512) {
        int cl = i / 90, r = i % 90;
        int c = cg * 64 + cl;
        float v;
        if (r < 9) {
            v = w_scale[c * 9 + r];
        } else {
            int j = (r - 9) / 9, k = (r - 9) % 9;
            v = w_mask[((size_t)(j * C_ + c)) * 9 + k];
        }
        wsm[i] = v;
    }
    __syncthreads();

    float acc[10];
#pragma unroll
    for (int o = 0; o < 10; ++o) acc[o] = 0.f;

    const float* xb = x + (size_t)b * (C_ * HW);
#pragma unroll 1
    for (int cc = 0; cc < 8; ++cc) {
        int cl = wv * 8 + cc;
        const float* xp = xb + (cg * 64 + cl) * HW;
        float xv[9];
#pragma unroll
        for (int dy = -1; dy <= 1; ++dy) {
            int hh = h + dy;
            bool hv = (hh >= 0) && (hh < 64);
#pragma unroll
            for (int dx = -1; dx <= 1; ++dx) {
                int ww = w + dx;
                bool vld = hv && (ww >= 0) && (ww < 64);
                xv[(dy + 1) * 3 + (dx + 1)] = vld ? xp[hh * 64 + ww] : 0.f;
            }
        }
        const float* wrow = &wsm[cl * 90];
#pragma unroll
        for (int k = 0; k < 9; ++k) acc[0] = fmaf(xv[k], wrow[k], acc[0]);
#pragma unroll
        for (int j = 0; j < 9; ++j) {
#pragma unroll
            for (int k = 0; k < 9; ++k)
                acc[1 + j] = fmaf(xv[k], wrow[9 + j * 9 + k], acc[1 + j]);
        }
    }

#pragma unroll
    for (int o = 0; o < 10; ++o) red[(o * 8 + wv) * 64 + w] = acc[o];
    __syncthreads();
    if (tid < 64) {
        float* pout = part + ((size_t)(cg * 256 + bh) * 10) * 64 + tid;
#pragma unroll
        for (int o = 0; o < 10; ++o) {
            float t = 0.f;
#pragma unroll
            for (int g = 0; g < 8; ++g) t += red[(o * 8 + g) * 64 + tid];
            pout[o * 64] = t;
        }
    }
}

// ---------------- Kernel 1b: finalize scale/mask ----------------
__global__ __launch_bounds__(256) void k_finalize(
    const float* __restrict__ part, const float* __restrict__ b_scale,
    const float* __restrict__ b_mask, float* __restrict__ scale_o,
    float* __restrict__ mask_o)
{
    int tid = threadIdx.x;
    int bh = blockIdx.x * 4 + (tid >> 6);
    int w = tid & 63;
    int b = bh >> 6, h = bh & 63;
#pragma unroll
    for (int o = 0; o < 10; ++o) {
        float t = 0.f;
#pragma unroll
        for (int cg = 0; cg < 4; ++cg)
            t += part[((size_t)(cg * 256 + bh) * 10 + o) * 64 + w];
        if (o == 0) {
            float s = t + b_scale[0];
            scale_o[bh * 64 + w] = s > 0.f ? s : 0.f;
        } else {
            float m = t + b_mask[o - 1];
            mask_o[(b * 9 + (o - 1)) * HW + h * 64 + w] = 1.f / (1.f + expf(-m));
        }
    }
}

// ---------------- Kernel 2: pack weight fp32 -> bf16, tap-major K ----------------
__global__ __launch_bounds__(256) void k_pack_w(const float* __restrict__ wgt,
                                                u16* __restrict__ wbf)
{
    int k = blockIdx.x, o = blockIdx.y, c = threadIdx.x;
    wbf[(size_t)o * K_ + k * 256 + c] = f2bf(wgt[(size_t)o * K_ + c * 9 + k]);
}

// ---------------- Kernel 2b: transpose x NCHW -> NHWC (xT[b][hw][c]) ----------------
__global__ __launch_bounds__(256) void k_transpose(const float* __restrict__ x,
                                                   float* __restrict__ xT)
{
    __shared__ float t[64][65];
    int tid = threadIdx.x;
    int hw0 = blockIdx.x * 64, c0 = blockIdx.y * 64, b = blockIdx.z;

    {
        int hw4 = (tid & 15) * 4;
        int cr = tid >> 4;                 // 0..15
        const float* xb = x + ((size_t)(b * 256 + c0)) * HW + hw0;
#pragma unroll
        for (int i = 0; i < 4; ++i) {
            int c = cr + i * 16;
            float4 v = *(const float4*)(xb + (size_t)c * HW + hw4);
            *(float4*)(&t[c][hw4]) = v;
        }
    }
    __syncthreads();
    {
        int c4 = (tid & 15) * 4;
        int hwr = tid >> 4;                // 0..15
        float* xo = xT + ((size_t)(b * HW + hw0)) * 256 + c0;
#pragma unroll
        for (int i = 0; i < 4; ++i) {
            int hwl = hwr + i * 16;
            float4 o;
            o.x = t[c4 + 0][hwl];
            o.y = t[c4 + 1][hwl];
            o.z = t[c4 + 2][hwl];
            o.w = t[c4 + 3][hwl];
            *(float4*)(xo + (size_t)hwl * 256 + c4) = o;
        }
    }
}

// ---------------- Kernel 3: build val[N][K] bf16 from NHWC x ----------------
__global__ __launch_bounds__(256) void k_val2(
    const float* __restrict__ xT, const float* __restrict__ scale_i,
    const float* __restrict__ mask_i, u16* __restrict__ val)
{
    int wv = threadIdx.x >> 6, lane = threadIdx.x & 63;
    int p = blockIdx.x * 4 + wv;
    int b = p >> 12, hw = p & 4095;
    int h = hw >> 6, w = hw & 63;
    float d = 1.f + scale_i[p];
    const float* xb = xT + ((size_t)(b << 12)) * 256;
    u16* vout = val + (size_t)p * K_;
    int c0 = lane * 4;

#pragma unroll 3
    for (int k = 0; k < 9; ++k) {
        int dy = k / 3 - 1, dx = k % 3 - 1;
        float ysf = (float)(h - 1) + (float)dy * d;
        float xsf = (float)(w - 1) + (float)dx * d;
        float y0f = floorf(ysf), x0f = floorf(xsf);
        float wy = ysf - y0f, wx = xsf - x0f;
        int y0 = (int)y0f, x0 = (int)x0f;
        int y1 = y0 + 1, x1 = x0 + 1;
        float vy0 = (y0 >= 0 && y0 < 64) ? 1.f : 0.f;
        float vy1 = (y1 >= 0 && y1 < 64) ? 1.f : 0.f;
        float vx0 = (x0 >= 0 && x0 < 64) ? 1.f : 0.f;
        float vx1 = (x1 >= 0 && x1 < 64) ? 1.f : 0.f;

        float m = mask_i[(b * 9 + k) * HW + hw];
        float w00 = (1.f - wy) * (1.f - wx) * m * vy0 * vx0;
        float w01 = (1.f - wy) * wx * m * vy0 * vx1;
        float w10 = wy * (1.f - wx) * m * vy1 * vx0;
        float w11 = wy * wx * m * vy1 * vx1;

        int cy0 = min(max(y0, 0), 63), cy1 = min(max(y1, 0), 63);
        int cx0 = min(max(x0, 0), 63), cx1 = min(max(x1, 0), 63);

        const float* p00 = xb + (size_t)(cy0 * 64 + cx0) * 256 + c0;
        const float* p01 = xb + (size_t)(cy0 * 64 + cx1) * 256 + c0;
        const float* p10 = xb + (size_t)(cy1 * 64 + cx0) * 256 + c0;
        const float* p11 = xb + (size_t)(cy1 * 64 + cx1) * 256 + c0;
        float4 v00 = *(const float4*)p00;
        float4 v01 = *(const float4*)p01;
        float4 v10 = *(const float4*)p10;
        float4 v11 = *(const float4*)p11;

        float rx = fmaf(w00, v00.x, fmaf(w01, v01.x, fmaf(w10, v10.x, w11 * v11.x)));
        float ry = fmaf(w00, v00.y, fmaf(w01, v01.y, fmaf(w10, v10.y, w11 * v11.y)));
        float rz = fmaf(w00, v00.z, fmaf(w01, v01.z, fmaf(w10, v10.z, w11 * v11.z)));
        float rw = fmaf(w00, v00.w, fmaf(w01, v01.w, fmaf(w10, v10.w, w11 * v11.w)));

        ushort4 pk;
        pk.x = f2bf(rx); pk.y = f2bf(ry); pk.z = f2bf(rz); pk.w = f2bf(rw);
        *(ushort4*)(vout + k * 256 + c0) = pk;
    }
}

// ---------------- Kernel 4: bf16 MFMA GEMM ----------------
__global__ __launch_bounds__(256) void k_gemm(
    const u16* __restrict__ wbf, const u16* __restrict__ val,
    const float* __restrict__ bias, float* __restrict__ out)
{
    __shared__ u16 As[128 * 40];
    __shared__ u16 Bs[128 * 40];
    int tid = threadIdx.x;
    int lane = tid & 63;
    int wv = tid >> 6;
    int wm = wv >> 1, wn = wv & 1;
    int n0 = blockIdx.x * 128;
    int m0 = blockIdx.y * 128;
    int l15 = lane & 15, l4 = lane >> 4;

    f32x4 acc[4][4];
#pragma unroll
    for (int i = 0; i < 4; ++i)
#pragma unroll
        for (int j = 0; j < 4; ++j) acc[i][j] = (f32x4){0.f, 0.f, 0.f, 0.f};

    int r0 = tid >> 2, q0 = tid & 3;
    int r1 = (tid + 256) >> 2;

    for (int k0 = 0; k0 < K_; k0 += 32) {
        uint4 a0 = *(const uint4*)(wbf + (size_t)(m0 + r0) * K_ + k0 + q0 * 8);
        uint4 a1 = *(const uint4*)(wbf + (size_t)(m0 + r1) * K_ + k0 + q0 * 8);
        uint4 b0 = *(const uint4*)(val + (size_t)(n0 + r0) * K_ + k0 + q0 * 8);
        uint4 b1 = *(const uint4*)(val + (size_t)(n0 + r1) * K_ + k0 + q0 * 8);
        __syncthreads();
        *(uint4*)(As + r0 * 40 + q0 * 8) = a0;
        *(uint4*)(As + r1 * 40 + q0 * 8) = a1;
        *(uint4*)(Bs + r0 * 40 + q0 * 8) = b0;
        *(uint4*)(Bs + r1 * 40 + q0 * 8) = b1;
        __syncthreads();

        bf16x8 af[4], bg[4];
#pragma unroll
        for (int i = 0; i < 4; ++i)
            af[i] = *(const bf16x8*)(As + (wm * 64 + i * 16 + l15) * 40 + l4 * 8);
#pragma unroll
        for (int j = 0; j < 4; ++j)
            bg[j] = *(const bf16x8*)(Bs + (wn * 64 + j * 16 + l15) * 40 + l4 * 8);
#pragma unroll
        for (int i = 0; i < 4; ++i)
#pragma unroll
            for (int j = 0; j < 4; ++j)
                acc[i][j] = __builtin_amdgcn_mfma_f32_16x16x32_bf16(af[i], bg[j], acc[i][j], 0, 0, 0);
    }

    int bidx = n0 >> 12;
    int hwbase = n0 & 4095;
#pragma unroll
    for (int i = 0; i < 4; ++i)
#pragma unroll
        for (int j = 0; j < 4; ++j)
#pragma unroll
            for (int t = 0; t < 4; ++t) {
                int row = wm * 64 + i * 16 + l4 * 4 + t;
                int col = wn * 64 + j * 16 + l15;
                int o = m0 + row;
                out[((size_t)(bidx * O_ + o)) * HW + hwbase + col] = acc[i][j][t] + bias[o];
            }
}

extern "C" void kernel_launch(void* const* d_in, const int* in_sizes, int n_in,
                              void* d_out, int out_size, void* d_ws, size_t ws_size,
                              hipStream_t stream) {
    const float* x       = (const float*)d_in[0];
    const float* weight  = (const float*)d_in[1];
    const float* bias    = (const float*)d_in[2];
    const float* w_scale = (const float*)d_in[3];
    const float* b_scale = (const float*)d_in[4];
    const float* w_mask  = (const float*)d_in[5];
    const float* b_mask  = (const float*)d_in[6];
    float* out = (float*)d_out;

    char* ws = (char*)d_ws;
    float* scale_ws = (float*)ws;                                  // 64 KB
    float* mask_ws  = (float*)(ws + 65536);                        // 576 KB
    u16*   wbf      = (u16*)(ws + 65536 + 589824);                 // 1.125 MB
    u16*   val      = (u16*)(ws + 65536 + 589824 + 1179648);       // 75.5 MB
    float* xT       = (float*)(ws + 65536 + 589824 + 1179648 + 75497472); // 64 MB
    // partials alias the val region: fully consumed by k_finalize before k_val2 writes val
    float* part_ws  = (float*)val;                                 // 2.62 MB

    k_scale_mask<<<dim3(B_ * H_, 4), 512, 0, stream>>>(x, w_scale, w_mask, part_ws);
    k_finalize<<<dim3(64), 256, 0, stream>>>(part_ws, b_scale, b_mask, scale_ws, mask_ws);
    k_pack_w<<<dim3(9, O_), 256, 0, stream>>>(weight, wbf);
    k_transpose<<<dim3(HW / 64, C_ / 64, B_), 256, 0, stream>>>(x, xT);
    k_val2<<<dim3(NPIX / 4), 256, 0, stream>>>(xT, scale_ws, mask_ws, val);
    k_gemm<<<dim3(NPIX / 128, O_ / 128), 256, 0, stream>>>(wbf, val, bias, out);
}

// Round 8
// 185.659 us; speedup vs baseline: 4.2477x; 1.0817x over previous
//
#include <hip/hip_runtime.h>
#include <stdint.h>

#define B_ 4
#define C_ 256
#define H_ 64
#define W_ 64
#define O_ 256
#define K_ 2304    // C_*9, tap-major: kk = k*256 + c
#define HW 4096
#define NPIX 16384

typedef unsigned short u16;
typedef __attribute__((ext_vector_type(8))) short bf16x8;
typedef __attribute__((ext_vector_type(4))) float f32x4;

__device__ __forceinline__ u16 f2bf(float f) {
    union { float f; uint32_t u; } v; v.f = f;
    uint32_t u = v.u;
    return (u16)((u + 0x7FFFu + ((u >> 16) & 1u)) >> 16);
}

// ---------------- Kernel 1: scale + mask conv3x3 (partial over 64-ch group) ----
// R5 lesson: was VMEM-instruction-bound (broadcast weight loads) -> LDS-stage weights.
// Channel loop stays rolled (R4: full unroll -> 1.8KB/thread scratch spill).
__global__ __launch_bounds__(512) void k_scale_mask(
    const float* __restrict__ x, const float* __restrict__ w_scale,
    const float* __restrict__ w_mask, float* __restrict__ part)
{
    __shared__ float wsm[64 * 90];   // [c_local][90]: 0..8 w_scale, 9+j*9+k w_mask
    __shared__ float red[10 * 8 * 64];

    int bh = blockIdx.x;           // 0..255
    int cg = blockIdx.y;           // 0..3
    int b = bh >> 6, h = bh & 63;
    int tid = threadIdx.x;
    int w = tid & 63;
    int wv = tid >> 6;             // 0..7

    for (int i = tid; i < 64 * 90; i += 512) {
        int cl = i / 90, r = i % 90;
        int c = cg * 64 + cl;
        float v;
        if (r < 9) {
            v = w_scale[c * 9 + r];
        } else {
            int j = (r - 9) / 9, k = (r - 9) % 9;
            v = w_mask[((size_t)(j * C_ + c)) * 9 + k];
        }
        wsm[i] = v;
    }
    __syncthreads();

    float acc[10];
#pragma unroll
    for (int o = 0; o < 10; ++o) acc[o] = 0.f;

    const float* xb = x + (size_t)b * (C_ * HW);
#pragma unroll 1
    for (int cc = 0; cc < 8; ++cc) {
        int cl = wv * 8 + cc;
        const float* xp = xb + (cg * 64 + cl) * HW;
        float xv[9];
#pragma unroll
        for (int dy = -1; dy <= 1; ++dy) {
            int hh = h + dy;
            bool hv = (hh >= 0) && (hh < 64);
#pragma unroll
            for (int dx = -1; dx <= 1; ++dx) {
                int ww = w + dx;
                bool vld = hv && (ww >= 0) && (ww < 64);
                xv[(dy + 1) * 3 + (dx + 1)] = vld ? xp[hh * 64 + ww] : 0.f;
            }
        }
        const float* wrow = &wsm[cl * 90];
#pragma unroll
        for (int k = 0; k < 9; ++k) acc[0] = fmaf(xv[k], wrow[k], acc[0]);
#pragma unroll
        for (int j = 0; j < 9; ++j) {
#pragma unroll
            for (int k = 0; k < 9; ++k)
                acc[1 + j] = fmaf(xv[k], wrow[9 + j * 9 + k], acc[1 + j]);
        }
    }

#pragma unroll
    for (int o = 0; o < 10; ++o) red[(o * 8 + wv) * 64 + w] = acc[o];
    __syncthreads();
    if (tid < 64) {
        float* pout = part + ((size_t)(cg * 256 + bh) * 10) * 64 + tid;
#pragma unroll
        for (int o = 0; o < 10; ++o) {
            float t = 0.f;
#pragma unroll
            for (int g = 0; g < 8; ++g) t += red[(o * 8 + g) * 64 + tid];
            pout[o * 64] = t;
        }
    }
}

// ---------------- Kernel 1b: finalize scale/mask ----------------
__global__ __launch_bounds__(256) void k_finalize(
    const float* __restrict__ part, const float* __restrict__ b_scale,
    const float* __restrict__ b_mask, float* __restrict__ scale_o,
    float* __restrict__ mask_o)
{
    int tid = threadIdx.x;
    int bh = blockIdx.x * 4 + (tid >> 6);
    int w = tid & 63;
    int b = bh >> 6, h = bh & 63;
#pragma unroll
    for (int o = 0; o < 10; ++o) {
        float t = 0.f;
#pragma unroll
        for (int cg = 0; cg < 4; ++cg)
            t += part[((size_t)(cg * 256 + bh) * 10 + o) * 64 + w];
        if (o == 0) {
            float s = t + b_scale[0];
            scale_o[bh * 64 + w] = s > 0.f ? s : 0.f;
        } else {
            float m = t + b_mask[o - 1];
            mask_o[(b * 9 + (o - 1)) * HW + h * 64 + w] = 1.f / (1.f + expf(-m));
        }
    }
}

// ---------------- Kernel 2: pack weight fp32 -> bf16, tap-major K ----------------
__global__ __launch_bounds__(256) void k_pack_w(const float* __restrict__ wgt,
                                                u16* __restrict__ wbf)
{
    int k = blockIdx.x, o = blockIdx.y, c = threadIdx.x;
    wbf[(size_t)o * K_ + k * 256 + c] = f2bf(wgt[(size_t)o * K_ + c * 9 + k]);
}

// ---------------- Kernel 2b: transpose x NCHW -> NHWC (xT[b][hw][c]) ----------------
__global__ __launch_bounds__(256) void k_transpose(const float* __restrict__ x,
                                                   float* __restrict__ xT)
{
    __shared__ float t[64][65];
    int tid = threadIdx.x;
    int hw0 = blockIdx.x * 64, c0 = blockIdx.y * 64, b = blockIdx.z;

    {
        int hw4 = (tid & 15) * 4;
        int cr = tid >> 4;                 // 0..15
        const float* xb = x + ((size_t)(b * 256 + c0)) * HW + hw0;
#pragma unroll
        for (int i = 0; i < 4; ++i) {
            int c = cr + i * 16;
            float4 v = *(const float4*)(xb + (size_t)c * HW + hw4);
            *(float4*)(&t[c][hw4]) = v;
        }
    }
    __syncthreads();
    {
        int c4 = (tid & 15) * 4;
        int hwr = tid >> 4;                // 0..15
        float* xo = xT + ((size_t)(b * HW + hw0)) * 256 + c0;
#pragma unroll
        for (int i = 0; i < 4; ++i) {
            int hwl = hwr + i * 16;
            float4 o;
            o.x = t[c4 + 0][hwl];
            o.y = t[c4 + 1][hwl];
            o.z = t[c4 + 2][hwl];
            o.w = t[c4 + 3][hwl];
            *(float4*)(xo + (size_t)hwl * 256 + c4) = o;
        }
    }
}

// ---------------- Kernel 3: build val[N][K] bf16 from NHWC x ----------------
__global__ __launch_bounds__(256) void k_val2(
    const float* __restrict__ xT, const float* __restrict__ scale_i,
    const float* __restrict__ mask_i, u16* __restrict__ val)
{
    int wv = threadIdx.x >> 6, lane = threadIdx.x & 63;
    int p = blockIdx.x * 4 + wv;
    int b = p >> 12, hw = p & 4095;
    int h = hw >> 6, w = hw & 63;
    float d = 1.f + scale_i[p];
    const float* xb = xT + ((size_t)(b << 12)) * 256;
    u16* vout = val + (size_t)p * K_;
    int c0 = lane * 4;

#pragma unroll 3
    for (int k = 0; k < 9; ++k) {
        int dy = k / 3 - 1, dx = k % 3 - 1;
        float ysf = (float)(h - 1) + (float)dy * d;
        float xsf = (float)(w - 1) + (float)dx * d;
        float y0f = floorf(ysf), x0f = floorf(xsf);
        float wy = ysf - y0f, wx = xsf - x0f;
        int y0 = (int)y0f, x0 = (int)x0f;
        int y1 = y0 + 1, x1 = x0 + 1;
        float vy0 = (y0 >= 0 && y0 < 64) ? 1.f : 0.f;
        float vy1 = (y1 >= 0 && y1 < 64) ? 1.f : 0.f;
        float vx0 = (x0 >= 0 && x0 < 64) ? 1.f : 0.f;
        float vx1 = (x1 >= 0 && x1 < 64) ? 1.f : 0.f;

        float m = mask_i[(b * 9 + k) * HW + hw];
        float w00 = (1.f - wy) * (1.f - wx) * m * vy0 * vx0;
        float w01 = (1.f - wy) * wx * m * vy0 * vx1;
        float w10 = wy * (1.f - wx) * m * vy1 * vx0;
        float w11 = wy * wx * m * vy1 * vx1;

        int cy0 = min(max(y0, 0), 63), cy1 = min(max(y1, 0), 63);
        int cx0 = min(max(x0, 0), 63), cx1 = min(max(x1, 0), 63);

        const float* p00 = xb + (size_t)(cy0 * 64 + cx0) * 256 + c0;
        const float* p01 = xb + (size_t)(cy0 * 64 + cx1) * 256 + c0;
        const float* p10 = xb + (size_t)(cy1 * 64 + cx0) * 256 + c0;
        const float* p11 = xb + (size_t)(cy1 * 64 + cx1) * 256 + c0;
        float4 v00 = *(const float4*)p00;
        float4 v01 = *(const float4*)p01;
        float4 v10 = *(const float4*)p10;
        float4 v11 = *(const float4*)p11;

        float rx = fmaf(w00, v00.x, fmaf(w01, v01.x, fmaf(w10, v10.x, w11 * v11.x)));
        float ry = fmaf(w00, v00.y, fmaf(w01, v01.y, fmaf(w10, v10.y, w11 * v11.y)));
        float rz = fmaf(w00, v00.z, fmaf(w01, v01.z, fmaf(w10, v10.z, w11 * v11.z)));
        float rw = fmaf(w00, v00.w, fmaf(w01, v01.w, fmaf(w10, v10.w, w11 * v11.w)));

        ushort4 pk;
        pk.x = f2bf(rx); pk.y = f2bf(ry); pk.z = f2bf(rz); pk.w = f2bf(rw);
        *(ushort4*)(vout + k * 256 + c0) = pk;
    }
}

// ---------------- Kernel 4: bf16 MFMA GEMM ----------------
// R6 lesson: 256 blocks = 1 block/CU = 1 wave/SIMD -> every vmcnt drain exposed
// (MfmaUtil 12%). Re-tile BM=128 BN=64 BK=64 -> 512 blocks = 2/CU so one block's
// load drain overlaps the other's MFMA phase. Padded LDS stride 72 (2-way, free).
__global__ __launch_bounds__(256, 2) void k_gemm(
    const u16* __restrict__ wbf, const u16* __restrict__ val,
    const float* __restrict__ bias, float* __restrict__ out)
{
    __shared__ u16 As[128 * 72];   // [row O][64 K-slice], stride 72
    __shared__ u16 Bs[64 * 72];    // [row pixel][64 K-slice]
    int tid = threadIdx.x;
    int lane = tid & 63;
    int wv = tid >> 6;
    int wm = wv >> 1, wn = wv & 1;       // wave: M-half (64), N-quarter (32)
    int n0 = blockIdx.x * 64;
    int m0 = blockIdx.y * 128;
    int l15 = lane & 15, l4 = lane >> 4;

    f32x4 acc[4][2];
#pragma unroll
    for (int i = 0; i < 4; ++i)
#pragma unroll
        for (int j = 0; j < 2; ++j) acc[i][j] = (f32x4){0.f, 0.f, 0.f, 0.f};

    int rr = tid >> 3;        // 0..31
    int c8 = (tid & 7) * 8;   // K-col offset

    for (int k0 = 0; k0 < K_; k0 += 64) {
        uint4 a0 = *(const uint4*)(wbf + (size_t)(m0 + rr) * K_ + k0 + c8);
        uint4 a1 = *(const uint4*)(wbf + (size_t)(m0 + rr + 32) * K_ + k0 + c8);
        uint4 a2 = *(const uint4*)(wbf + (size_t)(m0 + rr + 64) * K_ + k0 + c8);
        uint4 a3 = *(const uint4*)(wbf + (size_t)(m0 + rr + 96) * K_ + k0 + c8);
        uint4 b0 = *(const uint4*)(val + (size_t)(n0 + rr) * K_ + k0 + c8);
        uint4 b1 = *(const uint4*)(val + (size_t)(n0 + rr + 32) * K_ + k0 + c8);
        __syncthreads();           // protect previous iteration's LDS reads
        *(uint4*)(As + rr * 72 + c8) = a0;
        *(uint4*)(As + (rr + 32) * 72 + c8) = a1;
        *(uint4*)(As + (rr + 64) * 72 + c8) = a2;
        *(uint4*)(As + (rr + 96) * 72 + c8) = a3;
        *(uint4*)(Bs + rr * 72 + c8) = b0;
        *(uint4*)(Bs + (rr + 32) * 72 + c8) = b1;
        __syncthreads();

#pragma unroll
        for (int kk = 0; kk < 2; ++kk) {
            bf16x8 af[4], bg[2];
#pragma unroll
            for (int i = 0; i < 4; ++i)
                af[i] = *(const bf16x8*)(As + (wm * 64 + i * 16 + l15) * 72 + kk * 32 + l4 * 8);
#pragma unroll
            for (int j = 0; j < 2; ++j)
                bg[j] = *(const bf16x8*)(Bs + (wn * 32 + j * 16 + l15) * 72 + kk * 32 + l4 * 8);
#pragma unroll
            for (int i = 0; i < 4; ++i)
#pragma unroll
                for (int j = 0; j < 2; ++j)
                    acc[i][j] = __builtin_amdgcn_mfma_f32_16x16x32_bf16(af[i], bg[j], acc[i][j], 0, 0, 0);
        }
    }

    int bidx = n0 >> 12;           // BN=64 tile never crosses a batch boundary
    int hwbase = n0 & 4095;
#pragma unroll
    for (int i = 0; i < 4; ++i)
#pragma unroll
        for (int j = 0; j < 2; ++j)
#pragma unroll
            for (int t = 0; t < 4; ++t) {
                int row = wm * 64 + i * 16 + l4 * 4 + t;
                int col = wn * 32 + j * 16 + l15;
                int o = m0 + row;
                out[((size_t)(bidx * O_ + o)) * HW + hwbase + col] = acc[i][j][t] + bias[o];
            }
}

extern "C" void kernel_launch(void* const* d_in, const int* in_sizes, int n_in,
                              void* d_out, int out_size, void* d_ws, size_t ws_size,
                              hipStream_t stream) {
    const float* x       = (const float*)d_in[0];
    const float* weight  = (const float*)d_in[1];
    const float* bias    = (const float*)d_in[2];
    const float* w_scale = (const float*)d_in[3];
    const float* b_scale = (const float*)d_in[4];
    const float* w_mask  = (const float*)d_in[5];
    const float* b_mask  = (const float*)d_in[6];
    float* out = (float*)d_out;

    char* ws = (char*)d_ws;
    float* scale_ws = (float*)ws;                                  // 64 KB
    float* mask_ws  = (float*)(ws + 65536);                        // 576 KB
    u16*   wbf      = (u16*)(ws + 65536 + 589824);                 // 1.125 MB
    u16*   val      = (u16*)(ws + 65536 + 589824 + 1179648);       // 75.5 MB
    float* xT       = (float*)(ws + 65536 + 589824 + 1179648 + 75497472); // 64 MB
    // partials alias the val region: fully consumed by k_finalize before k_val2 writes val
    float* part_ws  = (float*)val;                                 // 2.62 MB

    k_scale_mask<<<dim3(B_ * H_, 4), 512, 0, stream>>>(x, w_scale, w_mask, part_ws);
    k_finalize<<<dim3(64), 256, 0, stream>>>(part_ws, b_scale, b_mask, scale_ws, mask_ws);
    k_pack_w<<<dim3(9, O_), 256, 0, stream>>>(weight, wbf);
    k_transpose<<<dim3(HW / 64, C_ / 64, B_), 256, 0, stream>>>(x, xT);
    k_val2<<<dim3(NPIX / 4), 256, 0, stream>>>(xT, scale_ws, mask_ws, val);
    k_gemm<<<dim3(NPIX / 64, O_ / 128), 256, 0, stream>>>(wbf, val, bias, out);
}

// Round 9
// 175.394 us; speedup vs baseline: 4.4963x; 1.0585x over previous
//
#include <hip/hip_runtime.h>
#include <stdint.h>

#define B_ 4
#define C_ 256
#define H_ 64
#define W_ 64
#define O_ 256
#define K_ 2304    // C_*9, tap-major: kk = k*256 + c
#define HW 4096
#define NPIX 16384

typedef unsigned short u16;
typedef __attribute__((ext_vector_type(8))) short bf16x8;
typedef __attribute__((ext_vector_type(4))) float f32x4;

__device__ __forceinline__ u16 f2bf(float f) {
    union { float f; uint32_t u; } v; v.f = f;
    uint32_t u = v.u;
    return (u16)((u + 0x7FFFu + ((u >> 16) & 1u)) >> 16);
}
__device__ __forceinline__ float bf2f(u16 u) {
    union { uint32_t u; float f; } v; v.u = ((uint32_t)u) << 16;
    return v.f;
}

// ---------------- Kernel 1: scale + mask conv3x3 (partial over 64-ch group) ----
// R5 lesson: was VMEM-instruction-bound (broadcast weight loads) -> LDS-stage weights.
// Channel loop stays rolled (R4: full unroll -> 1.8KB/thread scratch spill).
__global__ __launch_bounds__(512) void k_scale_mask(
    const float* __restrict__ x, const float* __restrict__ w_scale,
    const float* __restrict__ w_mask, float* __restrict__ part)
{
    __shared__ float wsm[64 * 90];   // [c_local][90]: 0..8 w_scale, 9+j*9+k w_mask
    __shared__ float red[10 * 8 * 64];

    int bh = blockIdx.x;           // 0..255
    int cg = blockIdx.y;           // 0..3
    int b = bh >> 6, h = bh & 63;
    int tid = threadIdx.x;
    int w = tid & 63;
    int wv = tid >> 6;             // 0..7

    for (int i = tid; i < 64 * 90; i += 512) {
        int cl = i / 90, r = i % 90;
        int c = cg * 64 + cl;
        float v;
        if (r < 9) {
            v = w_scale[c * 9 + r];
        } else {
            int j = (r - 9) / 9, k = (r - 9) % 9;
            v = w_mask[((size_t)(j * C_ + c)) * 9 + k];
        }
        wsm[i] = v;
    }
    __syncthreads();

    float acc[10];
#pragma unroll
    for (int o = 0; o < 10; ++o) acc[o] = 0.f;

    const float* xb = x + (size_t)b * (C_ * HW);
#pragma unroll 1
    for (int cc = 0; cc < 8; ++cc) {
        int cl = wv * 8 + cc;
        const float* xp = xb + (cg * 64 + cl) * HW;
        float xv[9];
#pragma unroll
        for (int dy = -1; dy <= 1; ++dy) {
            int hh = h + dy;
            bool hv = (hh >= 0) && (hh < 64);
#pragma unroll
            for (int dx = -1; dx <= 1; ++dx) {
                int ww = w + dx;
                bool vld = hv && (ww >= 0) && (ww < 64);
                xv[(dy + 1) * 3 + (dx + 1)] = vld ? xp[hh * 64 + ww] : 0.f;
            }
        }
        const float* wrow = &wsm[cl * 90];
#pragma unroll
        for (int k = 0; k < 9; ++k) acc[0] = fmaf(xv[k], wrow[k], acc[0]);
#pragma unroll
        for (int j = 0; j < 9; ++j) {
#pragma unroll
            for (int k = 0; k < 9; ++k)
                acc[1 + j] = fmaf(xv[k], wrow[9 + j * 9 + k], acc[1 + j]);
        }
    }

#pragma unroll
    for (int o = 0; o < 10; ++o) red[(o * 8 + wv) * 64 + w] = acc[o];
    __syncthreads();
    if (tid < 64) {
        float* pout = part + ((size_t)(cg * 256 + bh) * 10) * 64 + tid;
#pragma unroll
        for (int o = 0; o < 10; ++o) {
            float t = 0.f;
#pragma unroll
            for (int g = 0; g < 8; ++g) t += red[(o * 8 + g) * 64 + tid];
            pout[o * 64] = t;
        }
    }
}

// ---------------- Kernel 1b: finalize scale/mask ----------------
__global__ __launch_bounds__(256) void k_finalize(
    const float* __restrict__ part, const float* __restrict__ b_scale,
    const float* __restrict__ b_mask, float* __restrict__ scale_o,
    float* __restrict__ mask_o)
{
    int tid = threadIdx.x;
    int bh = blockIdx.x * 4 + (tid >> 6);
    int w = tid & 63;
    int b = bh >> 6, h = bh & 63;
#pragma unroll
    for (int o = 0; o < 10; ++o) {
        float t = 0.f;
#pragma unroll
        for (int cg = 0; cg < 4; ++cg)
            t += part[((size_t)(cg * 256 + bh) * 10 + o) * 64 + w];
        if (o == 0) {
            float s = t + b_scale[0];
            scale_o[bh * 64 + w] = s > 0.f ? s : 0.f;
        } else {
            float m = t + b_mask[o - 1];
            mask_o[(b * 9 + (o - 1)) * HW + h * 64 + w] = 1.f / (1.f + expf(-m));
        }
    }
}

// ---------------- Kernel 2: pack weight fp32 -> bf16, tap-major K ----------------
__global__ __launch_bounds__(256) void k_pack_w(const float* __restrict__ wgt,
                                                u16* __restrict__ wbf)
{
    int k = blockIdx.x, o = blockIdx.y, c = threadIdx.x;
    wbf[(size_t)o * K_ + k * 256 + c] = f2bf(wgt[(size_t)o * K_ + c * 9 + k]);
}

// ---------------- Kernel 2b: transpose x NCHW fp32 -> NHWC bf16 (xT[b][hw][c]) ---
// R8: emit bf16 (halves write traffic 64->32MB and val2's gather bytes).
__global__ __launch_bounds__(256) void k_transpose(const float* __restrict__ x,
                                                   u16* __restrict__ xT)
{
    __shared__ float t[64][65];
    int tid = threadIdx.x;
    int hw0 = blockIdx.x * 64, c0 = blockIdx.y * 64, b = blockIdx.z;

    {
        int hw4 = (tid & 15) * 4;
        int cr = tid >> 4;                 // 0..15
        const float* xb = x + ((size_t)(b * 256 + c0)) * HW + hw0;
#pragma unroll
        for (int i = 0; i < 4; ++i) {
            int c = cr + i * 16;
            float4 v = *(const float4*)(xb + (size_t)c * HW + hw4);
            *(float4*)(&t[c][hw4]) = v;
        }
    }
    __syncthreads();
    {
        int c4 = (tid & 15) * 4;
        int hwr = tid >> 4;                // 0..15
        u16* xo = xT + ((size_t)(b * HW + hw0)) * 256 + c0;
#pragma unroll
        for (int i = 0; i < 4; ++i) {
            int hwl = hwr + i * 16;
            ushort4 o;
            o.x = f2bf(t[c4 + 0][hwl]);
            o.y = f2bf(t[c4 + 1][hwl]);
            o.z = f2bf(t[c4 + 2][hwl]);
            o.w = f2bf(t[c4 + 3][hwl]);
            *(ushort4*)(xo + (size_t)hwl * 256 + c4) = o;
        }
    }
}

// ---------------- Kernel 3: build val[N][K] bf16 from NHWC bf16 x ----------------
__global__ __launch_bounds__(256) void k_val2(
    const u16* __restrict__ xT, const float* __restrict__ scale_i,
    const float* __restrict__ mask_i, u16* __restrict__ val)
{
    int wv = threadIdx.x >> 6, lane = threadIdx.x & 63;
    int p = blockIdx.x * 4 + wv;
    int b = p >> 12, hw = p & 4095;
    int h = hw >> 6, w = hw & 63;
    float d = 1.f + scale_i[p];
    const u16* xb = xT + ((size_t)(b << 12)) * 256;
    u16* vout = val + (size_t)p * K_;
    int c0 = lane * 4;

#pragma unroll 3
    for (int k = 0; k < 9; ++k) {
        int dy = k / 3 - 1, dx = k % 3 - 1;
        float ysf = (float)(h - 1) + (float)dy * d;
        float xsf = (float)(w - 1) + (float)dx * d;
        float y0f = floorf(ysf), x0f = floorf(xsf);
        float wy = ysf - y0f, wx = xsf - x0f;
        int y0 = (int)y0f, x0 = (int)x0f;
        int y1 = y0 + 1, x1 = x0 + 1;
        float vy0 = (y0 >= 0 && y0 < 64) ? 1.f : 0.f;
        float vy1 = (y1 >= 0 && y1 < 64) ? 1.f : 0.f;
        float vx0 = (x0 >= 0 && x0 < 64) ? 1.f : 0.f;
        float vx1 = (x1 >= 0 && x1 < 64) ? 1.f : 0.f;

        float m = mask_i[(b * 9 + k) * HW + hw];
        float w00 = (1.f - wy) * (1.f - wx) * m * vy0 * vx0;
        float w01 = (1.f - wy) * wx * m * vy0 * vx1;
        float w10 = wy * (1.f - wx) * m * vy1 * vx0;
        float w11 = wy * wx * m * vy1 * vx1;

        int cy0 = min(max(y0, 0), 63), cy1 = min(max(y1, 0), 63);
        int cx0 = min(max(x0, 0), 63), cx1 = min(max(x1, 0), 63);

        const u16* p00 = xb + (size_t)(cy0 * 64 + cx0) * 256 + c0;
        const u16* p01 = xb + (size_t)(cy0 * 64 + cx1) * 256 + c0;
        const u16* p10 = xb + (size_t)(cy1 * 64 + cx0) * 256 + c0;
        const u16* p11 = xb + (size_t)(cy1 * 64 + cx1) * 256 + c0;
        ushort4 v00 = *(const ushort4*)p00;
        ushort4 v01 = *(const ushort4*)p01;
        ushort4 v10 = *(const ushort4*)p10;
        ushort4 v11 = *(const ushort4*)p11;

        float rx = fmaf(w00, bf2f(v00.x), fmaf(w01, bf2f(v01.x), fmaf(w10, bf2f(v10.x), w11 * bf2f(v11.x))));
        float ry = fmaf(w00, bf2f(v00.y), fmaf(w01, bf2f(v01.y), fmaf(w10, bf2f(v10.y), w11 * bf2f(v11.y))));
        float rz = fmaf(w00, bf2f(v00.z), fmaf(w01, bf2f(v01.z), fmaf(w10, bf2f(v10.z), w11 * bf2f(v11.z))));
        float rw = fmaf(w00, bf2f(v00.w), fmaf(w01, bf2f(v01.w), fmaf(w10, bf2f(v10.w), w11 * bf2f(v11.w))));

        ushort4 pk;
        pk.x = f2bf(rx); pk.y = f2bf(ry); pk.z = f2bf(rz); pk.w = f2bf(rw);
        *(ushort4*)(vout + k * 256 + c0) = pk;
    }
}

// ---------------- Kernel 4: bf16 MFMA GEMM ----------------
// R6 lesson: 1 block/CU exposed all latency (MfmaUtil 12%). BM=128 BN=64 BK=64
// -> 512 blocks = 2/CU; cross-block overlap hides vmcnt drains. Stride 72 pad.
__global__ __launch_bounds__(256, 2) void k_gemm(
    const u16* __restrict__ wbf, const u16* __restrict__ val,
    const float* __restrict__ bias, float* __restrict__ out)
{
    __shared__ u16 As[128 * 72];   // [row O][64 K-slice], stride 72
    __shared__ u16 Bs[64 * 72];    // [row pixel][64 K-slice]
    int tid = threadIdx.x;
    int lane = tid & 63;
    int wv = tid >> 6;
    int wm = wv >> 1, wn = wv & 1;       // wave: M-half (64), N-quarter (32)
    int n0 = blockIdx.x * 64;
    int m0 = blockIdx.y * 128;
    int l15 = lane & 15, l4 = lane >> 4;

    f32x4 acc[4][2];
#pragma unroll
    for (int i = 0; i < 4; ++i)
#pragma unroll
        for (int j = 0; j < 2; ++j) acc[i][j] = (f32x4){0.f, 0.f, 0.f, 0.f};

    int rr = tid >> 3;        // 0..31
    int c8 = (tid & 7) * 8;   // K-col offset

    for (int k0 = 0; k0 < K_; k0 += 64) {
        uint4 a0 = *(const uint4*)(wbf + (size_t)(m0 + rr) * K_ + k0 + c8);
        uint4 a1 = *(const uint4*)(wbf + (size_t)(m0 + rr + 32) * K_ + k0 + c8);
        uint4 a2 = *(const uint4*)(wbf + (size_t)(m0 + rr + 64) * K_ + k0 + c8);
        uint4 a3 = *(const uint4*)(wbf + (size_t)(m0 + rr + 96) * K_ + k0 + c8);
        uint4 b0 = *(const uint4*)(val + (size_t)(n0 + rr) * K_ + k0 + c8);
        uint4 b1 = *(const uint4*)(val + (size_t)(n0 + rr + 32) * K_ + k0 + c8);
        __syncthreads();           // protect previous iteration's LDS reads
        *(uint4*)(As + rr * 72 + c8) = a0;
        *(uint4*)(As + (rr + 32) * 72 + c8) = a1;
        *(uint4*)(As + (rr + 64) * 72 + c8) = a2;
        *(uint4*)(As + (rr + 96) * 72 + c8) = a3;
        *(uint4*)(Bs + rr * 72 + c8) = b0;
        *(uint4*)(Bs + (rr + 32) * 72 + c8) = b1;
        __syncthreads();

#pragma unroll
        for (int kk = 0; kk < 2; ++kk) {
            bf16x8 af[4], bg[2];
#pragma unroll
            for (int i = 0; i < 4; ++i)
                af[i] = *(const bf16x8*)(As + (wm * 64 + i * 16 + l15) * 72 + kk * 32 + l4 * 8);
#pragma unroll
            for (int j = 0; j < 2; ++j)
                bg[j] = *(const bf16x8*)(Bs + (wn * 32 + j * 16 + l15) * 72 + kk * 32 + l4 * 8);
#pragma unroll
            for (int i = 0; i < 4; ++i)
#pragma unroll
                for (int j = 0; j < 2; ++j)
                    acc[i][j] = __builtin_amdgcn_mfma_f32_16x16x32_bf16(af[i], bg[j], acc[i][j], 0, 0, 0);
        }
    }

    int bidx = n0 >> 12;           // BN=64 tile never crosses a batch boundary
    int hwbase = n0 & 4095;
#pragma unroll
    for (int i = 0; i < 4; ++i)
#pragma unroll
        for (int j = 0; j < 2; ++j)
#pragma unroll
            for (int t = 0; t < 4; ++t) {
                int row = wm * 64 + i * 16 + l4 * 4 + t;
                int col = wn * 32 + j * 16 + l15;
                int o = m0 + row;
                out[((size_t)(bidx * O_ + o)) * HW + hwbase + col] = acc[i][j][t] + bias[o];
            }
}

extern "C" void kernel_launch(void* const* d_in, const int* in_sizes, int n_in,
                              void* d_out, int out_size, void* d_ws, size_t ws_size,
                              hipStream_t stream) {
    const float* x       = (const float*)d_in[0];
    const float* weight  = (const float*)d_in[1];
    const float* bias    = (const float*)d_in[2];
    const float* w_scale = (const float*)d_in[3];
    const float* b_scale = (const float*)d_in[4];
    const float* w_mask  = (const float*)d_in[5];
    const float* b_mask  = (const float*)d_in[6];
    float* out = (float*)d_out;

    char* ws = (char*)d_ws;
    float* scale_ws = (float*)ws;                                  // 64 KB
    float* mask_ws  = (float*)(ws + 65536);                        // 576 KB
    u16*   wbf      = (u16*)(ws + 65536 + 589824);                 // 1.125 MB
    u16*   val      = (u16*)(ws + 65536 + 589824 + 1179648);       // 75.5 MB
    u16*   xT       = (u16*)(ws + 65536 + 589824 + 1179648 + 75497472); // 32 MB bf16
    // partials alias the val region: fully consumed by k_finalize before k_val2 writes val
    float* part_ws  = (float*)val;                                 // 2.62 MB

    k_scale_mask<<<dim3(B_ * H_, 4), 512, 0, stream>>>(x, w_scale, w_mask, part_ws);
    k_finalize<<<dim3(64), 256, 0, stream>>>(part_ws, b_scale, b_mask, scale_ws, mask_ws);
    k_pack_w<<<dim3(9, O_), 256, 0, stream>>>(weight, wbf);
    k_transpose<<<dim3(HW / 64, C_ / 64, B_), 256, 0, stream>>>(x, xT);
    k_val2<<<dim3(NPIX / 4), 256, 0, stream>>>(xT, scale_ws, mask_ws, val);
    k_gemm<<<dim3(NPIX / 64, O_ / 128), 256, 0, stream>>>(wbf, val, bias, out);
}

// Round 10
// 174.368 us; speedup vs baseline: 4.5228x; 1.0059x over previous
//
#include <hip/hip_runtime.h>
#include <stdint.h>

#define B_ 4
#define C_ 256
#define H_ 64
#define W_ 64
#define O_ 256
#define K_ 2304    // C_*9, tap-major: kk = k*256 + c
#define HW 4096
#define NPIX 16384

typedef unsigned short u16;
typedef __attribute__((ext_vector_type(8))) short bf16x8;
typedef __attribute__((ext_vector_type(4))) float f32x4;

__device__ __forceinline__ u16 f2bf(float f) {
    union { float f; uint32_t u; } v; v.f = f;
    uint32_t u = v.u;
    return (u16)((u + 0x7FFFu + ((u >> 16) & 1u)) >> 16);
}
__device__ __forceinline__ float bf2f(u16 u) {
    union { uint32_t u; float f; } v; v.u = ((uint32_t)u) << 16;
    return v.f;
}

// ---------------- Kernel 1: scale + mask conv3x3 + fused NHWC-bf16 transpose ----
// grid (B*H, 4). R5: LDS-stage weights (was VMEM-bound). R4: channel loop stays
// rolled (unroll -> 1.8KB/thread spill). R9: center tap xv[4] IS the transpose
// input -> stash in LDS tile, cooperative coalesced write to xT (kills the
// separate k_transpose kernel + one full x re-read).
__global__ __launch_bounds__(512) void k_scale_mask(
    const float* __restrict__ x, const float* __restrict__ w_scale,
    const float* __restrict__ w_mask, float* __restrict__ part,
    u16* __restrict__ xT)
{
    __shared__ float wsm[64 * 90];   // [c_local][90]: 0..8 w_scale, 9+j*9+k w_mask
    __shared__ float red[10 * 8 * 64];
    __shared__ u16 xt[64 * 72];      // [w][cl], row stride 72 u16 = 144B (16B-mult)

    int bh = blockIdx.x;           // 0..255
    int cg = blockIdx.y;           // 0..3
    int b = bh >> 6, h = bh & 63;
    int tid = threadIdx.x;
    int w = tid & 63;
    int wv = tid >> 6;             // 0..7

    for (int i = tid; i < 64 * 90; i += 512) {
        int cl = i / 90, r = i % 90;
        int c = cg * 64 + cl;
        float v;
        if (r < 9) {
            v = w_scale[c * 9 + r];
        } else {
            int j = (r - 9) / 9, k = (r - 9) % 9;
            v = w_mask[((size_t)(j * C_ + c)) * 9 + k];
        }
        wsm[i] = v;
    }
    __syncthreads();

    float acc[10];
#pragma unroll
    for (int o = 0; o < 10; ++o) acc[o] = 0.f;

    const float* xb = x + (size_t)b * (C_ * HW);
#pragma unroll 1
    for (int cc = 0; cc < 8; ++cc) {
        int cl = wv * 8 + cc;
        const float* xp = xb + (cg * 64 + cl) * HW;
        float xv[9];
#pragma unroll
        for (int dy = -1; dy <= 1; ++dy) {
            int hh = h + dy;
            bool hv = (hh >= 0) && (hh < 64);
#pragma unroll
            for (int dx = -1; dx <= 1; ++dx) {
                int ww = w + dx;
                bool vld = hv && (ww >= 0) && (ww < 64);
                xv[(dy + 1) * 3 + (dx + 1)] = vld ? xp[hh * 64 + ww] : 0.f;
            }
        }
        xt[w * 72 + cl] = f2bf(xv[4]);   // center tap -> transpose tile
        const float* wrow = &wsm[cl * 90];
#pragma unroll
        for (int k = 0; k < 9; ++k) acc[0] = fmaf(xv[k], wrow[k], acc[0]);
#pragma unroll
        for (int j = 0; j < 9; ++j) {
#pragma unroll
            for (int k = 0; k < 9; ++k)
                acc[1 + j] = fmaf(xv[k], wrow[9 + j * 9 + k], acc[1 + j]);
        }
    }

#pragma unroll
    for (int o = 0; o < 10; ++o) red[(o * 8 + wv) * 64 + w] = acc[o];
    __syncthreads();

    // cooperative xT write: thread -> (pixel w, 8 consecutive channels), 16B coalesced
    {
        int ww = tid >> 3, c8 = (tid & 7) * 8;
        uint4 v = *(const uint4*)(xt + ww * 72 + c8);
        *(uint4*)(xT + ((size_t)(bh * 64 + ww)) * 256 + cg * 64 + c8) = v;
    }

    if (tid < 64) {
        float* pout = part + ((size_t)(cg * 256 + bh) * 10) * 64 + tid;
#pragma unroll
        for (int o = 0; o < 10; ++o) {
            float t = 0.f;
#pragma unroll
            for (int g = 0; g < 8; ++g) t += red[(o * 8 + g) * 64 + tid];
            pout[o * 64] = t;
        }
    }
}

// ---------------- Kernel 1b: finalize scale/mask ----------------
__global__ __launch_bounds__(256) void k_finalize(
    const float* __restrict__ part, const float* __restrict__ b_scale,
    const float* __restrict__ b_mask, float* __restrict__ scale_o,
    float* __restrict__ mask_o)
{
    int tid = threadIdx.x;
    int bh = blockIdx.x * 4 + (tid >> 6);
    int w = tid & 63;
    int b = bh >> 6, h = bh & 63;
#pragma unroll
    for (int o = 0; o < 10; ++o) {
        float t = 0.f;
#pragma unroll
        for (int cg = 0; cg < 4; ++cg)
            t += part[((size_t)(cg * 256 + bh) * 10 + o) * 64 + w];
        if (o == 0) {
            float s = t + b_scale[0];
            scale_o[bh * 64 + w] = s > 0.f ? s : 0.f;
        } else {
            float m = t + b_mask[o - 1];
            mask_o[(b * 9 + (o - 1)) * HW + h * 64 + w] = 1.f / (1.f + expf(-m));
        }
    }
}

// ---------------- Kernel 2: pack weight fp32 -> bf16, tap-major K ----------------
__global__ __launch_bounds__(256) void k_pack_w(const float* __restrict__ wgt,
                                                u16* __restrict__ wbf)
{
    int k = blockIdx.x, o = blockIdx.y, c = threadIdx.x;
    wbf[(size_t)o * K_ + k * 256 + c] = f2bf(wgt[(size_t)o * K_ + c * 9 + k]);
}

// ---------------- Kernel 3: build val[N][K] bf16 from NHWC bf16 x ----------------
__global__ __launch_bounds__(256) void k_val2(
    const u16* __restrict__ xT, const float* __restrict__ scale_i,
    const float* __restrict__ mask_i, u16* __restrict__ val)
{
    int wv = threadIdx.x >> 6, lane = threadIdx.x & 63;
    int p = blockIdx.x * 4 + wv;
    int b = p >> 12, hw = p & 4095;
    int h = hw >> 6, w = hw & 63;
    float d = 1.f + scale_i[p];
    const u16* xb = xT + ((size_t)(b << 12)) * 256;
    u16* vout = val + (size_t)p * K_;
    int c0 = lane * 4;

#pragma unroll 3
    for (int k = 0; k < 9; ++k) {
        int dy = k / 3 - 1, dx = k % 3 - 1;
        float ysf = (float)(h - 1) + (float)dy * d;
        float xsf = (float)(w - 1) + (float)dx * d;
        float y0f = floorf(ysf), x0f = floorf(xsf);
        float wy = ysf - y0f, wx = xsf - x0f;
        int y0 = (int)y0f, x0 = (int)x0f;
        int y1 = y0 + 1, x1 = x0 + 1;
        float vy0 = (y0 >= 0 && y0 < 64) ? 1.f : 0.f;
        float vy1 = (y1 >= 0 && y1 < 64) ? 1.f : 0.f;
        float vx0 = (x0 >= 0 && x0 < 64) ? 1.f : 0.f;
        float vx1 = (x1 >= 0 && x1 < 64) ? 1.f : 0.f;

        float m = mask_i[(b * 9 + k) * HW + hw];
        float w00 = (1.f - wy) * (1.f - wx) * m * vy0 * vx0;
        float w01 = (1.f - wy) * wx * m * vy0 * vx1;
        float w10 = wy * (1.f - wx) * m * vy1 * vx0;
        float w11 = wy * wx * m * vy1 * vx1;

        int cy0 = min(max(y0, 0), 63), cy1 = min(max(y1, 0), 63);
        int cx0 = min(max(x0, 0), 63), cx1 = min(max(x1, 0), 63);

        const u16* p00 = xb + (size_t)(cy0 * 64 + cx0) * 256 + c0;
        const u16* p01 = xb + (size_t)(cy0 * 64 + cx1) * 256 + c0;
        const u16* p10 = xb + (size_t)(cy1 * 64 + cx0) * 256 + c0;
        const u16* p11 = xb + (size_t)(cy1 * 64 + cx1) * 256 + c0;
        ushort4 v00 = *(const ushort4*)p00;
        ushort4 v01 = *(const ushort4*)p01;
        ushort4 v10 = *(const ushort4*)p10;
        ushort4 v11 = *(const ushort4*)p11;

        float rx = fmaf(w00, bf2f(v00.x), fmaf(w01, bf2f(v01.x), fmaf(w10, bf2f(v10.x), w11 * bf2f(v11.x))));
        float ry = fmaf(w00, bf2f(v00.y), fmaf(w01, bf2f(v01.y), fmaf(w10, bf2f(v10.y), w11 * bf2f(v11.y))));
        float rz = fmaf(w00, bf2f(v00.z), fmaf(w01, bf2f(v01.z), fmaf(w10, bf2f(v10.z), w11 * bf2f(v11.z))));
        float rw = fmaf(w00, bf2f(v00.w), fmaf(w01, bf2f(v01.w), fmaf(w10, bf2f(v10.w), w11 * bf2f(v11.w))));

        ushort4 pk;
        pk.x = f2bf(rx); pk.y = f2bf(ry); pk.z = f2bf(rz); pk.w = f2bf(rw);
        *(ushort4*)(vout + k * 256 + c0) = pk;
    }
}

// ---------------- Kernel 4: bf16 MFMA GEMM ----------------
// R6: 2 blocks/CU (BM=128 BN=64 BK=64). R9: register prefetch — issue next
// K-step's 6 loads right after the LDS-write barrier so their L2/L3 latency
// hides under this K-step's ds_read+MFMA phase (was serially exposed 36x).
__global__ __launch_bounds__(256, 2) void k_gemm(
    const u16* __restrict__ wbf, const u16* __restrict__ val,
    const float* __restrict__ bias, float* __restrict__ out)
{
    __shared__ u16 As[128 * 72];   // [row O][64 K-slice], stride 72
    __shared__ u16 Bs[64 * 72];    // [row pixel][64 K-slice]
    int tid = threadIdx.x;
    int lane = tid & 63;
    int wv = tid >> 6;
    int wm = wv >> 1, wn = wv & 1;       // wave: M-half (64), N-quarter (32)
    int n0 = blockIdx.x * 64;
    int m0 = blockIdx.y * 128;
    int l15 = lane & 15, l4 = lane >> 4;

    f32x4 acc[4][2];
#pragma unroll
    for (int i = 0; i < 4; ++i)
#pragma unroll
        for (int j = 0; j < 2; ++j) acc[i][j] = (f32x4){0.f, 0.f, 0.f, 0.f};

    int rr = tid >> 3;        // 0..31
    int c8 = (tid & 7) * 8;   // K-col offset

    const u16* ap = wbf + (size_t)(m0 + rr) * K_ + c8;
    const u16* bp = val + (size_t)(n0 + rr) * K_ + c8;

    uint4 ra0 = *(const uint4*)(ap);
    uint4 ra1 = *(const uint4*)(ap + (size_t)32 * K_);
    uint4 ra2 = *(const uint4*)(ap + (size_t)64 * K_);
    uint4 ra3 = *(const uint4*)(ap + (size_t)96 * K_);
    uint4 rb0 = *(const uint4*)(bp);
    uint4 rb1 = *(const uint4*)(bp + (size_t)32 * K_);

    for (int k0 = 0; k0 < K_; k0 += 64) {
        __syncthreads();           // previous iteration's LDS reads done
        *(uint4*)(As + rr * 72 + c8) = ra0;
        *(uint4*)(As + (rr + 32) * 72 + c8) = ra1;
        *(uint4*)(As + (rr + 64) * 72 + c8) = ra2;
        *(uint4*)(As + (rr + 96) * 72 + c8) = ra3;
        *(uint4*)(Bs + rr * 72 + c8) = rb0;
        *(uint4*)(Bs + (rr + 32) * 72 + c8) = rb1;
        __syncthreads();

        int kn = k0 + 64;
        if (kn < K_) {             // prefetch next K-step; latency hides under MFMA
            ra0 = *(const uint4*)(ap + kn);
            ra1 = *(const uint4*)(ap + (size_t)32 * K_ + kn);
            ra2 = *(const uint4*)(ap + (size_t)64 * K_ + kn);
            ra3 = *(const uint4*)(ap + (size_t)96 * K_ + kn);
            rb0 = *(const uint4*)(bp + kn);
            rb1 = *(const uint4*)(bp + (size_t)32 * K_ + kn);
        }

#pragma unroll
        for (int kk = 0; kk < 2; ++kk) {
            bf16x8 af[4], bg[2];
#pragma unroll
            for (int i = 0; i < 4; ++i)
                af[i] = *(const bf16x8*)(As + (wm * 64 + i * 16 + l15) * 72 + kk * 32 + l4 * 8);
#pragma unroll
            for (int j = 0; j < 2; ++j)
                bg[j] = *(const bf16x8*)(Bs + (wn * 32 + j * 16 + l15) * 72 + kk * 32 + l4 * 8);
#pragma unroll
            for (int i = 0; i < 4; ++i)
#pragma unroll
                for (int j = 0; j < 2; ++j)
                    acc[i][j] = __builtin_amdgcn_mfma_f32_16x16x32_bf16(af[i], bg[j], acc[i][j], 0, 0, 0);
        }
    }

    int bidx = n0 >> 12;           // BN=64 tile never crosses a batch boundary
    int hwbase = n0 & 4095;
#pragma unroll
    for (int i = 0; i < 4; ++i)
#pragma unroll
        for (int j = 0; j < 2; ++j)
#pragma unroll
            for (int t = 0; t < 4; ++t) {
                int row = wm * 64 + i * 16 + l4 * 4 + t;
                int col = wn * 32 + j * 16 + l15;
                int o = m0 + row;
                out[((size_t)(bidx * O_ + o)) * HW + hwbase + col] = acc[i][j][t] + bias[o];
            }
}

extern "C" void kernel_launch(void* const* d_in, const int* in_sizes, int n_in,
                              void* d_out, int out_size, void* d_ws, size_t ws_size,
                              hipStream_t stream) {
    const float* x       = (const float*)d_in[0];
    const float* weight  = (const float*)d_in[1];
    const float* bias    = (const float*)d_in[2];
    const float* w_scale = (const float*)d_in[3];
    const float* b_scale = (const float*)d_in[4];
    const float* w_mask  = (const float*)d_in[5];
    const float* b_mask  = (const float*)d_in[6];
    float* out = (float*)d_out;

    char* ws = (char*)d_ws;
    float* scale_ws = (float*)ws;                                  // 64 KB
    float* mask_ws  = (float*)(ws + 65536);                        // 576 KB
    u16*   wbf      = (u16*)(ws + 65536 + 589824);                 // 1.125 MB
    u16*   val      = (u16*)(ws + 65536 + 589824 + 1179648);       // 75.5 MB
    u16*   xT       = (u16*)(ws + 65536 + 589824 + 1179648 + 75497472); // 8.4 MB bf16
    // partials alias the val region: fully consumed by k_finalize before k_val2 writes val
    float* part_ws  = (float*)val;                                 // 2.62 MB

    k_scale_mask<<<dim3(B_ * H_, 4), 512, 0, stream>>>(x, w_scale, w_mask, part_ws, xT);
    k_finalize<<<dim3(64), 256, 0, stream>>>(part_ws, b_scale, b_mask, scale_ws, mask_ws);
    k_pack_w<<<dim3(9, O_), 256, 0, stream>>>(weight, wbf);
    k_val2<<<dim3(NPIX / 4), 256, 0, stream>>>(xT, scale_ws, mask_ws, val);
    k_gemm<<<dim3(NPIX / 64, O_ / 128), 256, 0, stream>>>(wbf, val, bias, out);
}

// Round 12
// 171.246 us; speedup vs baseline: 4.6052x; 1.0182x over previous
//
#include <hip/hip_runtime.h>
#include <stdint.h>

#define B_ 4
#define C_ 256
#define H_ 64
#define W_ 64
#define O_ 256
#define K_ 2304    // C_*9, tap-major: kk = k*256 + c
#define HW 4096
#define NPIX 16384

typedef unsigned short u16;
typedef __attribute__((ext_vector_type(8))) short bf16x8;
typedef __attribute__((ext_vector_type(4))) float f32x4;

__device__ __forceinline__ u16 f2bf(float f) {
    union { float f; uint32_t u; } v; v.f = f;
    uint32_t u = v.u;
    return (u16)((u + 0x7FFFu + ((u >> 16) & 1u)) >> 16);
}
__device__ __forceinline__ float bf2f(u16 u) {
    union { uint32_t u; float f; } v; v.u = ((uint32_t)u) << 16;
    return v.f;
}

// ---------------- Kernel 1: scale + mask conv3x3 + fused NHWC-bf16 transpose ----
// R5: LDS-stage weights (was VMEM-bound). R4: channel loop stays rolled
// (unroll -> spill). R9: fused transpose via center tap. R10: weight rows padded
// to 96 floats, read as 23x ds_read_b128 into static-indexed f32x4 regs
// (was 90x ds_read_b32/iter -> LDS-issue bound at 41us).
__global__ __launch_bounds__(512) void k_scale_mask(
    const float* __restrict__ x, const float* __restrict__ w_scale,
    const float* __restrict__ w_mask, float* __restrict__ part,
    u16* __restrict__ xT)
{
    __shared__ f32x4 wsm4[64 * 24];  // [c_local][96 floats]: 0..8 scale, 9+j*9+k mask, 90..95 pad
    __shared__ float red[10 * 8 * 64];
    __shared__ u16 xt[64 * 72];      // [w][cl], row stride 72 u16 = 144B (16B-mult)

    int bh = blockIdx.x;           // 0..255
    int cg = blockIdx.y;           // 0..3
    int b = bh >> 6, h = bh & 63;
    int tid = threadIdx.x;
    int w = tid & 63;
    int wv = tid >> 6;             // 0..7

    float* wsm = (float*)wsm4;
    for (int i = tid; i < 64 * 96; i += 512) {
        int cl = i / 96, r = i % 96;
        int c = cg * 64 + cl;
        float v = 0.f;
        if (r < 9) {
            v = w_scale[c * 9 + r];
        } else if (r < 90) {
            int j = (r - 9) / 9, k = (r - 9) % 9;
            v = w_mask[((size_t)(j * C_ + c)) * 9 + k];
        }
        wsm[i] = v;
    }
    __syncthreads();

    float acc[10];
#pragma unroll
    for (int o = 0; o < 10; ++o) acc[o] = 0.f;

    const float* xb = x + (size_t)b * (C_ * HW);
#pragma unroll 1
    for (int cc = 0; cc < 8; ++cc) {
        int cl = wv * 8 + cc;
        const float* xp = xb + (cg * 64 + cl) * HW;
        float xv[9];
#pragma unroll
        for (int dy = -1; dy <= 1; ++dy) {
            int hh = h + dy;
            bool hv = (hh >= 0) && (hh < 64);
#pragma unroll
            for (int dx = -1; dx <= 1; ++dx) {
                int ww = w + dx;
                bool vld = hv && (ww >= 0) && (ww < 64);
                xv[(dy + 1) * 3 + (dx + 1)] = vld ? xp[hh * 64 + ww] : 0.f;
            }
        }
        xt[w * 72 + cl] = f2bf(xv[4]);   // center tap -> transpose tile

        const f32x4* wr4 = wsm4 + cl * 24;
        f32x4 wq[23];
#pragma unroll
        for (int q = 0; q < 23; ++q) wq[q] = wr4[q];   // 23x ds_read_b128 broadcast

#pragma unroll
        for (int k = 0; k < 9; ++k)
            acc[0] = fmaf(xv[k], wq[k >> 2][k & 3], acc[0]);
#pragma unroll
        for (int j = 0; j < 9; ++j) {
#pragma unroll
            for (int k = 0; k < 9; ++k) {
                int r = 9 + j * 9 + k;                  // compile-time after unroll
                acc[1 + j] = fmaf(xv[k], wq[r >> 2][r & 3], acc[1 + j]);
            }
        }
    }

#pragma unroll
    for (int o = 0; o < 10; ++o) red[(o * 8 + wv) * 64 + w] = acc[o];
    __syncthreads();

    // cooperative xT write: thread -> (pixel w, 8 consecutive channels), 16B coalesced
    {
        int ww = tid >> 3, c8 = (tid & 7) * 8;
        uint4 v = *(const uint4*)(xt + ww * 72 + c8);
        *(uint4*)(xT + ((size_t)(bh * 64 + ww)) * 256 + cg * 64 + c8) = v;
    }

    if (tid < 64) {
        float* pout = part + ((size_t)(cg * 256 + bh) * 10) * 64 + tid;
#pragma unroll
        for (int o = 0; o < 10; ++o) {
            float t = 0.f;
#pragma unroll
            for (int g = 0; g < 8; ++g) t += red[(o * 8 + g) * 64 + tid];
            pout[o * 64] = t;
        }
    }
}

// ---------------- Kernel 1b: finalize scale/mask ----------------
__global__ __launch_bounds__(256) void k_finalize(
    const float* __restrict__ part, const float* __restrict__ b_scale,
    const float* __restrict__ b_mask, float* __restrict__ scale_o,
    float* __restrict__ mask_o)
{
    int tid = threadIdx.x;
    int bh = blockIdx.x * 4 + (tid >> 6);
    int w = tid & 63;
    int b = bh >> 6, h = bh & 63;
#pragma unroll
    for (int o = 0; o < 10; ++o) {
        float t = 0.f;
#pragma unroll
        for (int cg = 0; cg < 4; ++cg)
            t += part[((size_t)(cg * 256 + bh) * 10 + o) * 64 + w];
        if (o == 0) {
            float s = t + b_scale[0];
            scale_o[bh * 64 + w] = s > 0.f ? s : 0.f;
        } else {
            float m = t + b_mask[o - 1];
            mask_o[(b * 9 + (o - 1)) * HW + h * 64 + w] = 1.f / (1.f + expf(-m));
        }
    }
}

// ---------------- Kernel 2: pack weight fp32 -> bf16, tap-major K ----------------
__global__ __launch_bounds__(256) void k_pack_w(const float* __restrict__ wgt,
                                                u16* __restrict__ wbf)
{
    int k = blockIdx.x, o = blockIdx.y, c = threadIdx.x;
    wbf[(size_t)o * K_ + k * 256 + c] = f2bf(wgt[(size_t)o * K_ + c * 9 + k]);
}

// ---------------- Kernel 3: build val[N][K] bf16 from NHWC bf16 x ----------------
__global__ __launch_bounds__(256) void k_val2(
    const u16* __restrict__ xT, const float* __restrict__ scale_i,
    const float* __restrict__ mask_i, u16* __restrict__ val)
{
    int wv = threadIdx.x >> 6, lane = threadIdx.x & 63;
    int p = blockIdx.x * 4 + wv;
    int b = p >> 12, hw = p & 4095;
    int h = hw >> 6, w = hw & 63;
    float d = 1.f + scale_i[p];
    const u16* xb = xT + ((size_t)(b << 12)) * 256;
    u16* vout = val + (size_t)p * K_;
    int c0 = lane * 4;

#pragma unroll 3
    for (int k = 0; k < 9; ++k) {
        int dy = k / 3 - 1, dx = k % 3 - 1;
        float ysf = (float)(h - 1) + (float)dy * d;
        float xsf = (float)(w - 1) + (float)dx * d;
        float y0f = floorf(ysf), x0f = floorf(xsf);
        float wy = ysf - y0f, wx = xsf - x0f;
        int y0 = (int)y0f, x0 = (int)x0f;
        int y1 = y0 + 1, x1 = x0 + 1;
        float vy0 = (y0 >= 0 && y0 < 64) ? 1.f : 0.f;
        float vy1 = (y1 >= 0 && y1 < 64) ? 1.f : 0.f;
        float vx0 = (x0 >= 0 && x0 < 64) ? 1.f : 0.f;
        float vx1 = (x1 >= 0 && x1 < 64) ? 1.f : 0.f;

        float m = mask_i[(b * 9 + k) * HW + hw];
        float w00 = (1.f - wy) * (1.f - wx) * m * vy0 * vx0;
        float w01 = (1.f - wy) * wx * m * vy0 * vx1;
        float w10 = wy * (1.f - wx) * m * vy1 * vx0;
        float w11 = wy * wx * m * vy1 * vx1;

        int cy0 = min(max(y0, 0), 63), cy1 = min(max(y1, 0), 63);
        int cx0 = min(max(x0, 0), 63), cx1 = min(max(x1, 0), 63);

        const u16* p00 = xb + (size_t)(cy0 * 64 + cx0) * 256 + c0;
        const u16* p01 = xb + (size_t)(cy0 * 64 + cx1) * 256 + c0;
        const u16* p10 = xb + (size_t)(cy1 * 64 + cx0) * 256 + c0;
        const u16* p11 = xb + (size_t)(cy1 * 64 + cx1) * 256 + c0;
        ushort4 v00 = *(const ushort4*)p00;
        ushort4 v01 = *(const ushort4*)p01;
        ushort4 v10 = *(const ushort4*)p10;
        ushort4 v11 = *(const ushort4*)p11;

        float rx = fmaf(w00, bf2f(v00.x), fmaf(w01, bf2f(v01.x), fmaf(w10, bf2f(v10.x), w11 * bf2f(v11.x))));
        float ry = fmaf(w00, bf2f(v00.y), fmaf(w01, bf2f(v01.y), fmaf(w10, bf2f(v10.y), w11 * bf2f(v11.y))));
        float rz = fmaf(w00, bf2f(v00.z), fmaf(w01, bf2f(v01.z), fmaf(w10, bf2f(v10.z), w11 * bf2f(v11.z))));
        float rw = fmaf(w00, bf2f(v00.w), fmaf(w01, bf2f(v01.w), fmaf(w10, bf2f(v10.w), w11 * bf2f(v11.w))));

        ushort4 pk;
        pk.x = f2bf(rx); pk.y = f2bf(ry); pk.z = f2bf(rz); pk.w = f2bf(rw);
        *(ushort4*)(vout + k * 256 + c0) = pk;
    }
}

// ---------------- Kernel 4: bf16 MFMA GEMM ----------------
// R6: 2 blocks/CU (BM=128 BN=64 BK=64). R9: register prefetch of next K-step.
__global__ __launch_bounds__(256, 2) void k_gemm(
    const u16* __restrict__ wbf, const u16* __restrict__ val,
    const float* __restrict__ bias, float* __restrict__ out)
{
    __shared__ u16 As[128 * 72];   // [row O][64 K-slice], stride 72
    __shared__ u16 Bs[64 * 72];    // [row pixel][64 K-slice]
    int tid = threadIdx.x;
    int lane = tid & 63;
    int wv = tid >> 6;
    int wm = wv >> 1, wn = wv & 1;       // wave: M-half (64), N-quarter (32)
    int n0 = blockIdx.x * 64;
    int m0 = blockIdx.y * 128;
    int l15 = lane & 15, l4 = lane >> 4;

    f32x4 acc[4][2];
#pragma unroll
    for (int i = 0; i < 4; ++i)
#pragma unroll
        for (int j = 0; j < 2; ++j) acc[i][j] = (f32x4){0.f, 0.f, 0.f, 0.f};

    int rr = tid >> 3;        // 0..31
    int c8 = (tid & 7) * 8;   // K-col offset

    const u16* ap = wbf + (size_t)(m0 + rr) * K_ + c8;
    const u16* bp = val + (size_t)(n0 + rr) * K_ + c8;

    uint4 ra0 = *(const uint4*)(ap);
    uint4 ra1 = *(const uint4*)(ap + (size_t)32 * K_);
    uint4 ra2 = *(const uint4*)(ap + (size_t)64 * K_);
    uint4 ra3 = *(const uint4*)(ap + (size_t)96 * K_);
    uint4 rb0 = *(const uint4*)(bp);
    uint4 rb1 = *(const uint4*)(bp + (size_t)32 * K_);

    for (int k0 = 0; k0 < K_; k0 += 64) {
        __syncthreads();           // previous iteration's LDS reads done
        *(uint4*)(As + rr * 72 + c8) = ra0;
        *(uint4*)(As + (rr + 32) * 72 + c8) = ra1;
        *(uint4*)(As + (rr + 64) * 72 + c8) = ra2;
        *(uint4*)(As + (rr + 96) * 72 + c8) = ra3;
        *(uint4*)(Bs + rr * 72 + c8) = rb0;
        *(uint4*)(Bs + (rr + 32) * 72 + c8) = rb1;
        __syncthreads();

        int kn = k0 + 64;
        if (kn < K_) {             // prefetch next K-step; latency hides under MFMA
            ra0 = *(const uint4*)(ap + kn);
            ra1 = *(const uint4*)(ap + (size_t)32 * K_ + kn);
            ra2 = *(const uint4*)(ap + (size_t)64 * K_ + kn);
            ra3 = *(const uint4*)(ap + (size_t)96 * K_ + kn);
            rb0 = *(const uint4*)(bp + kn);
            rb1 = *(const uint4*)(bp + (size_t)32 * K_ + kn);
        }

#pragma unroll
        for (int kk = 0; kk < 2; ++kk) {
            bf16x8 af[4], bg[2];
#pragma unroll
            for (int i = 0; i < 4; ++i)
                af[i] = *(const bf16x8*)(As + (wm * 64 + i * 16 + l15) * 72 + kk * 32 + l4 * 8);
#pragma unroll
            for (int j = 0; j < 2; ++j)
                bg[j] = *(const bf16x8*)(Bs + (wn * 32 + j * 16 + l15) * 72 + kk * 32 + l4 * 8);
#pragma unroll
            for (int i = 0; i < 4; ++i)
#pragma unroll
                for (int j = 0; j < 2; ++j)
                    acc[i][j] = __builtin_amdgcn_mfma_f32_16x16x32_bf16(af[i], bg[j], acc[i][j], 0, 0, 0);
        }
    }

    int bidx = n0 >> 12;           // BN=64 tile never crosses a batch boundary
    int hwbase = n0 & 4095;
#pragma unroll
    for (int i = 0; i < 4; ++i)
#pragma unroll
        for (int j = 0; j < 2; ++j)
#pragma unroll
            for (int t = 0; t < 4; ++t) {
                int row = wm * 64 + i * 16 + l4 * 4 + t;
                int col = wn * 32 + j * 16 + l15;
                int o = m0 + row;
                out[((size_t)(bidx * O_ + o)) * HW + hwbase + col] = acc[i][j][t] + bias[o];
            }
}

extern "C" void kernel_launch(void* const* d_in, const int* in_sizes, int n_in,
                              void* d_out, int out_size, void* d_ws, size_t ws_size,
                              hipStream_t stream) {
    const float* x       = (const float*)d_in[0];
    const float* weight  = (const float*)d_in[1];
    const float* bias    = (const float*)d_in[2];
    const float* w_scale = (const float*)d_in[3];
    const float* b_scale = (const float*)d_in[4];
    const float* w_mask  = (const float*)d_in[5];
    const float* b_mask  = (const float*)d_in[6];
    float* out = (float*)d_out;

    char* ws = (char*)d_ws;
    float* scale_ws = (float*)ws;                                  // 64 KB
    float* mask_ws  = (float*)(ws + 65536);                        // 576 KB
    u16*   wbf      = (u16*)(ws + 65536 + 589824);                 // 1.125 MB
    u16*   val      = (u16*)(ws + 65536 + 589824 + 1179648);       // 75.5 MB
    u16*   xT       = (u16*)(ws + 65536 + 589824 + 1179648 + 75497472); // 8.4 MB bf16
    // partials alias the val region: fully consumed by k_finalize before k_val2 writes val
    float* part_ws  = (float*)val;                                 // 2.62 MB

    k_scale_mask<<<dim3(B_ * H_, 4), 512, 0, stream>>>(x, w_scale, w_mask, part_ws, xT);
    k_finalize<<<dim3(64), 256, 0, stream>>>(part_ws, b_scale, b_mask, scale_ws, mask_ws);
    k_pack_w<<<dim3(9, O_), 256, 0, stream>>>(weight, wbf);
    k_val2<<<dim3(NPIX / 4), 256, 0, stream>>>(xT, scale_ws, mask_ws, val);
    k_gemm<<<dim3(NPIX / 64, O_ / 128), 256, 0, stream>>>(wbf, val, bias, out);
}

// Round 14
// 165.216 us; speedup vs baseline: 4.7733x; 1.0365x over previous
//
#include <hip/hip_runtime.h>
#include <stdint.h>

#define B_ 4
#define C_ 256
#define H_ 64
#define W_ 64
#define O_ 256
#define K_ 2304    // C_*9, tap-major: kk = k*256 + c
#define HW 4096
#define NPIX 16384

typedef unsigned short u16;
typedef __attribute__((ext_vector_type(8))) short bf16x8;
typedef __attribute__((ext_vector_type(4))) float f32x4;

__device__ __forceinline__ u16 f2bf(float f) {
    union { float f; uint32_t u; } v; v.f = f;
    uint32_t u = v.u;
    return (u16)((u + 0x7FFFu + ((u >> 16) & 1u)) >> 16);
}
__device__ __forceinline__ float bflo(uint32_t u) {
    union { uint32_t u; float f; } v; v.u = u << 16; return v.f;
}
__device__ __forceinline__ float bfhi(uint32_t u) {
    union { uint32_t u; float f; } v; v.u = u & 0xffff0000u; return v.f;
}

// ---------------- Kernel 1: scale + mask conv3x3 + fused NHWC-bf16 transpose ----
// R5: LDS-stage weights. R4: channel loop rolled (unroll -> spill). R9: fused
// transpose via center tap. R10: weights as 23x ds_read_b128 static-indexed regs.
__global__ __launch_bounds__(512) void k_scale_mask(
    const float* __restrict__ x, const float* __restrict__ w_scale,
    const float* __restrict__ w_mask, float* __restrict__ part,
    u16* __restrict__ xT)
{
    __shared__ f32x4 wsm4[64 * 24];  // [c_local][96 floats]: 0..8 scale, 9+j*9+k mask
    __shared__ float red[10 * 8 * 64];
    __shared__ u16 xt[64 * 72];      // [w][cl], row stride 72 u16

    int bh = blockIdx.x;           // 0..255
    int cg = blockIdx.y;           // 0..3
    int b = bh >> 6, h = bh & 63;
    int tid = threadIdx.x;
    int w = tid & 63;
    int wv = tid >> 6;             // 0..7

    float* wsm = (float*)wsm4;
    for (int i = tid; i < 64 * 96; i += 512) {
        int cl = i / 96, r = i % 96;
        int c = cg * 64 + cl;
        float v = 0.f;
        if (r < 9) {
            v = w_scale[c * 9 + r];
        } else if (r < 90) {
            int j = (r - 9) / 9, k = (r - 9) % 9;
            v = w_mask[((size_t)(j * C_ + c)) * 9 + k];
        }
        wsm[i] = v;
    }
    __syncthreads();

    float acc[10];
#pragma unroll
    for (int o = 0; o < 10; ++o) acc[o] = 0.f;

    const float* xb = x + (size_t)b * (C_ * HW);
#pragma unroll 1
    for (int cc = 0; cc < 8; ++cc) {
        int cl = wv * 8 + cc;
        const float* xp = xb + (cg * 64 + cl) * HW;
        float xv[9];
#pragma unroll
        for (int dy = -1; dy <= 1; ++dy) {
            int hh = h + dy;
            bool hv = (hh >= 0) && (hh < 64);
#pragma unroll
            for (int dx = -1; dx <= 1; ++dx) {
                int ww = w + dx;
                bool vld = hv && (ww >= 0) && (ww < 64);
                xv[(dy + 1) * 3 + (dx + 1)] = vld ? xp[hh * 64 + ww] : 0.f;
            }
        }
        xt[w * 72 + cl] = f2bf(xv[4]);   // center tap -> transpose tile

        const f32x4* wr4 = wsm4 + cl * 24;
        f32x4 wq[23];
#pragma unroll
        for (int q = 0; q < 23; ++q) wq[q] = wr4[q];

#pragma unroll
        for (int k = 0; k < 9; ++k)
            acc[0] = fmaf(xv[k], wq[k >> 2][k & 3], acc[0]);
#pragma unroll
        for (int j = 0; j < 9; ++j) {
#pragma unroll
            for (int k = 0; k < 9; ++k) {
                int r = 9 + j * 9 + k;
                acc[1 + j] = fmaf(xv[k], wq[r >> 2][r & 3], acc[1 + j]);
            }
        }
    }

#pragma unroll
    for (int o = 0; o < 10; ++o) red[(o * 8 + wv) * 64 + w] = acc[o];
    __syncthreads();

    {
        int ww = tid >> 3, c8 = (tid & 7) * 8;
        uint4 v = *(const uint4*)(xt + ww * 72 + c8);
        *(uint4*)(xT + ((size_t)(bh * 64 + ww)) * 256 + cg * 64 + c8) = v;
    }

    if (tid < 64) {
        float* pout = part + ((size_t)(cg * 256 + bh) * 10) * 64 + tid;
#pragma unroll
        for (int o = 0; o < 10; ++o) {
            float t = 0.f;
#pragma unroll
            for (int g = 0; g < 8; ++g) t += red[(o * 8 + g) * 64 + tid];
            pout[o * 64] = t;
        }
    }
}

// ---------------- Kernel 1b: finalize scale/mask ----------------
__global__ __launch_bounds__(256) void k_finalize(
    const float* __restrict__ part, const float* __restrict__ b_scale,
    const float* __restrict__ b_mask, float* __restrict__ scale_o,
    float* __restrict__ mask_o)
{
    int tid = threadIdx.x;
    int bh = blockIdx.x * 4 + (tid >> 6);
    int w = tid & 63;
    int b = bh >> 6, h = bh & 63;
#pragma unroll
    for (int o = 0; o < 10; ++o) {
        float t = 0.f;
#pragma unroll
        for (int cg = 0; cg < 4; ++cg)
            t += part[((size_t)(cg * 256 + bh) * 10 + o) * 64 + w];
        if (o == 0) {
            float s = t + b_scale[0];
            scale_o[bh * 64 + w] = s > 0.f ? s : 0.f;
        } else {
            float m = t + b_mask[o - 1];
            mask_o[(b * 9 + (o - 1)) * HW + h * 64 + w] = 1.f / (1.f + expf(-m));
        }
    }
}

// ---------------- Kernel 2: pack weight fp32 -> bf16, tap-major K ----------------
__global__ __launch_bounds__(256) void k_pack_w(const float* __restrict__ wgt,
                                                u16* __restrict__ wbf)
{
    int k = blockIdx.x, o = blockIdx.y, c = threadIdx.x;
    wbf[(size_t)o * K_ + k * 256 + c] = f2bf(wgt[(size_t)o * K_ + c * 9 + k]);
}

// ---------------- bilinear 8-channel sample -> packed bf16x8 ----------------
__device__ __forceinline__ uint4 bilin8(const u16* __restrict__ xb, int cb,
    int i00, int i01, int i10, int i11,
    float w00, float w01, float w10, float w11)
{
    uint4 u00 = *(const uint4*)(xb + (size_t)i00 * 256 + cb);
    uint4 u01 = *(const uint4*)(xb + (size_t)i01 * 256 + cb);
    uint4 u10 = *(const uint4*)(xb + (size_t)i10 * 256 + cb);
    uint4 u11 = *(const uint4*)(xb + (size_t)i11 * 256 + cb);
    const uint32_t* p00 = &u00.x;
    const uint32_t* p01 = &u01.x;
    const uint32_t* p10 = &u10.x;
    const uint32_t* p11 = &u11.x;
    uint4 r;
    uint32_t* pr = &r.x;
#pragma unroll
    for (int i = 0; i < 4; ++i) {
        float lo = fmaf(w00, bflo(p00[i]), fmaf(w01, bflo(p01[i]),
                   fmaf(w10, bflo(p10[i]), w11 * bflo(p11[i]))));
        float hi = fmaf(w00, bfhi(p00[i]), fmaf(w01, bfhi(p01[i]),
                   fmaf(w10, bfhi(p10[i]), w11 * bfhi(p11[i]))));
        pr[i] = (uint32_t)f2bf(lo) | ((uint32_t)f2bf(hi) << 16);
    }
    return r;
}

// per-pixel per-tap coords/weights (identical math+order to old k_val2)
__device__ __forceinline__ void tapcoord(int h, int w, float d, float mm,
    int dy, int dx, float& w00, float& w01, float& w10, float& w11,
    int& i00, int& i01, int& i10, int& i11)
{
    float ys = (float)(h - 1) + (float)dy * d;
    float xs = (float)(w - 1) + (float)dx * d;
    float y0f = floorf(ys), x0f = floorf(xs);
    float wy = ys - y0f, wx = xs - x0f;
    int y0 = (int)y0f, x0 = (int)x0f;
    int y1 = y0 + 1, x1 = x0 + 1;
    float vy0 = (y0 >= 0 && y0 < 64) ? 1.f : 0.f;
    float vy1 = (y1 >= 0 && y1 < 64) ? 1.f : 0.f;
    float vx0 = (x0 >= 0 && x0 < 64) ? 1.f : 0.f;
    float vx1 = (x1 >= 0 && x1 < 64) ? 1.f : 0.f;
    w00 = (1.f - wy) * (1.f - wx) * mm * vy0 * vx0;
    w01 = (1.f - wy) * wx * mm * vy0 * vx1;
    w10 = wy * (1.f - wx) * mm * vy1 * vx0;
    w11 = wy * wx * mm * vy1 * vx1;
    int cy0 = min(max(y0, 0), 63), cy1 = min(max(y1, 0), 63);
    int cx0 = min(max(x0, 0), 63), cx1 = min(max(x1, 0), 63);
    i00 = cy0 * 64 + cx0; i01 = cy0 * 64 + cx1;
    i10 = cy1 * 64 + cx0; i11 = cy1 * 64 + cx1;
}

// ---------------- Kernel 3: fused im2col + bf16 MFMA GEMM ----------------
// R12: BK=64 slice = one tap x 64 channels -> sample B-tile on the fly from
// NHWC bf16 xT into Bs. Deletes k_val2 + 75.5MB write + ~151MB read.
// Coords/weights recomputed on tap change only (every 4 K-steps, uniform).
__global__ __launch_bounds__(256, 2) void k_gemm_fused(
    const u16* __restrict__ wbf, const u16* __restrict__ xT,
    const float* __restrict__ scale_i, const float* __restrict__ mask_i,
    const float* __restrict__ bias, float* __restrict__ out)
{
    __shared__ u16 As[128 * 72];   // [row O][64 K-slice], stride 72
    __shared__ u16 Bs[64 * 72];    // [row pixel][64 K-slice]
    int tid = threadIdx.x;
    int lane = tid & 63;
    int wv = tid >> 6;
    int wm = wv >> 1, wn = wv & 1;
    int n0 = blockIdx.x * 64;
    int m0 = blockIdx.y * 128;
    int l15 = lane & 15, l4 = lane >> 4;

    f32x4 acc[4][2];
#pragma unroll
    for (int i = 0; i < 4; ++i)
#pragma unroll
        for (int j = 0; j < 2; ++j) acc[i][j] = (f32x4){0.f, 0.f, 0.f, 0.f};

    int rr = tid >> 3;        // 0..31  (pixels n0+rr, n0+rr+32)
    int c8 = (tid & 7) * 8;   // channel offset within BK slice

    int b = n0 >> 12;         // BN=64 never crosses batch boundary
    int hw0 = (n0 & 4095) + rr;
    int hw1 = hw0 + 32;
    int h0 = hw0 >> 6, w0c = hw0 & 63;
    int h1 = hw1 >> 6, w1c = hw1 & 63;
    float d0 = 1.f + scale_i[n0 + rr];
    float d1 = 1.f + scale_i[n0 + rr + 32];
    const u16* xb = xT + (((size_t)b) << 12) * 256;
    const float* mrow = mask_i + (size_t)b * 9 * HW;

    const u16* ap = wbf + (size_t)(m0 + rr) * K_ + c8;

    float w00a, w01a, w10a, w11a, w00b, w01b, w10b, w11b;
    int i00a, i01a, i10a, i11a, i00b, i01b, i10b, i11b;

    for (int k0 = 0; k0 < K_; k0 += 64) {
        int tap = k0 >> 8;
        if ((k0 & 255) == 0) {      // tap changed (uniform branch)
            int dy = tap / 3 - 1, dx = tap % 3 - 1;
            float mm0 = mrow[tap * HW + hw0];
            float mm1 = mrow[tap * HW + hw1];
            tapcoord(h0, w0c, d0, mm0, dy, dx, w00a, w01a, w10a, w11a,
                     i00a, i01a, i10a, i11a);
            tapcoord(h1, w1c, d1, mm1, dy, dx, w00b, w01b, w10b, w11b,
                     i00b, i01b, i10b, i11b);
        }
        int cb = (k0 & 255) + c8;

        uint4 a0 = *(const uint4*)(ap + k0);
        uint4 a1 = *(const uint4*)(ap + (size_t)32 * K_ + k0);
        uint4 a2 = *(const uint4*)(ap + (size_t)64 * K_ + k0);
        uint4 a3 = *(const uint4*)(ap + (size_t)96 * K_ + k0);

        uint4 r0 = bilin8(xb, cb, i00a, i01a, i10a, i11a, w00a, w01a, w10a, w11a);
        uint4 r1 = bilin8(xb, cb, i00b, i01b, i10b, i11b, w00b, w01b, w10b, w11b);

        __syncthreads();           // previous iteration's LDS reads done
        *(uint4*)(As + rr * 72 + c8) = a0;
        *(uint4*)(As + (rr + 32) * 72 + c8) = a1;
        *(uint4*)(As + (rr + 64) * 72 + c8) = a2;
        *(uint4*)(As + (rr + 96) * 72 + c8) = a3;
        *(uint4*)(Bs + rr * 72 + c8) = r0;
        *(uint4*)(Bs + (rr + 32) * 72 + c8) = r1;
        __syncthreads();

#pragma unroll
        for (int kk = 0; kk < 2; ++kk) {
            bf16x8 af[4], bg[2];
#pragma unroll
            for (int i = 0; i < 4; ++i)
                af[i] = *(const bf16x8*)(As + (wm * 64 + i * 16 + l15) * 72 + kk * 32 + l4 * 8);
#pragma unroll
            for (int j = 0; j < 2; ++j)
                bg[j] = *(const bf16x8*)(Bs + (wn * 32 + j * 16 + l15) * 72 + kk * 32 + l4 * 8);
#pragma unroll
            for (int i = 0; i < 4; ++i)
#pragma unroll
                for (int j = 0; j < 2; ++j)
                    acc[i][j] = __builtin_amdgcn_mfma_f32_16x16x32_bf16(af[i], bg[j], acc[i][j], 0, 0, 0);
        }
    }

    int hwbase = n0 & 4095;
#pragma unroll
    for (int i = 0; i < 4; ++i)
#pragma unroll
        for (int j = 0; j < 2; ++j)
#pragma unroll
            for (int t = 0; t < 4; ++t) {
                int row = wm * 64 + i * 16 + l4 * 4 + t;
                int col = wn * 32 + j * 16 + l15;
                int o = m0 + row;
                out[((size_t)(b * O_ + o)) * HW + hwbase + col] = acc[i][j][t] + bias[o];
            }
}

extern "C" void kernel_launch(void* const* d_in, const int* in_sizes, int n_in,
                              void* d_out, int out_size, void* d_ws, size_t ws_size,
                              hipStream_t stream) {
    const float* x       = (const float*)d_in[0];
    const float* weight  = (const float*)d_in[1];
    const float* bias    = (const float*)d_in[2];
    const float* w_scale = (const float*)d_in[3];
    const float* b_scale = (const float*)d_in[4];
    const float* w_mask  = (const float*)d_in[5];
    const float* b_mask  = (const float*)d_in[6];
    float* out = (float*)d_out;

    char* ws = (char*)d_ws;
    float* scale_ws = (float*)ws;                                  // 64 KB
    float* mask_ws  = (float*)(ws + 65536);                        // 576 KB
    u16*   wbf      = (u16*)(ws + 65536 + 589824);                 // 1.125 MB
    float* part_ws  = (float*)(ws + 65536 + 589824 + 1179648);     // 2.62 MB
    u16*   xT       = (u16*)(ws + 65536 + 589824 + 1179648 + 75497472); // 8.4 MB bf16

    k_scale_mask<<<dim3(B_ * H_, 4), 512, 0, stream>>>(x, w_scale, w_mask, part_ws, xT);
    k_finalize<<<dim3(64), 256, 0, stream>>>(part_ws, b_scale, b_mask, scale_ws, mask_ws);
    k_pack_w<<<dim3(9, O_), 256, 0, stream>>>(weight, wbf);
    k_gemm_fused<<<dim3(NPIX / 64, O_ / 128), 256, 0, stream>>>(wbf, xT, scale_ws,
                                                                mask_ws, bias, out);
}